// Round 1
// baseline (462.593 us; speedup 1.0000x reference)
//
#include <hip/hip_runtime.h>
#include <cstdint>

static constexpr int DD = 256;   // feature dim (fixed by problem)

// ---------------- CSR build ----------------

__global__ void k_count(const int* __restrict__ vertex, const int* __restrict__ edges,
                        int* __restrict__ cntV, int* __restrict__ cntE, int nnz) {
  int i = blockIdx.x * blockDim.x + threadIdx.x;
  if (i < nnz) {
    atomicAdd(&cntV[vertex[i]], 1);
    atomicAdd(&cntE[edges[i]], 1);
  }
}

__global__ __launch_bounds__(1024) void k_scan(const int* __restrict__ cnt,
                                               int* __restrict__ offs,
                                               int* __restrict__ cursor, int n) {
  const int BS = 1024;
  __shared__ int sh[BS];
  int t = threadIdx.x;
  int chunk = (n + BS - 1) / BS;
  int lo = t * chunk;
  int hi = min(lo + chunk, n);
  int s = 0;
  for (int i = lo; i < hi; ++i) s += cnt[i];
  sh[t] = s;
  __syncthreads();
  // Hillis-Steele inclusive scan over 1024 partials
  for (int off = 1; off < BS; off <<= 1) {
    int v = (t >= off) ? sh[t - off] : 0;
    __syncthreads();
    sh[t] += v;
    __syncthreads();
  }
  int excl = (t == 0) ? 0 : sh[t - 1];
  for (int i = lo; i < hi; ++i) {
    offs[i] = excl;
    cursor[i] = excl;
    excl += cnt[i];
  }
  if (t == BS - 1) offs[n] = excl;
}

__global__ void k_fill(const int* __restrict__ vertex, const int* __restrict__ edges,
                       int* __restrict__ curE, int* __restrict__ curV,
                       int* __restrict__ incEv, int* __restrict__ incVe, int nnz) {
  int i = blockIdx.x * blockDim.x + threadIdx.x;
  if (i < nnz) {
    int v = vertex[i], e = edges[i];
    int pe = atomicAdd(&curE[e], 1);
    incEv[pe] = v;              // per-edge list of member vertices
    int pv = atomicAdd(&curV[v], 1);
    incVe[pv] = e;              // per-vertex list of incident edges
  }
}

// ---------------- hop 1: mean-aggregate vertices into edges ----------------
// one 64-lane wave per edge; float4 per lane covers D=256

__global__ void k_hop1(const float* __restrict__ X, const float* __restrict__ degE,
                       const int* __restrict__ offsE, const int* __restrict__ incEv,
                       float* __restrict__ Xe, int M) {
  int gw = (blockIdx.x * blockDim.x + threadIdx.x) >> 6;
  int lane = threadIdx.x & 63;
  if (gw >= M) return;
  int s = offsE[gw], t = offsE[gw + 1];
  float ax = 0.f, ay = 0.f, az = 0.f, aw = 0.f;
  const float* Xl = X + lane * 4;
  for (int k = s; k < t; ++k) {
    int v = incEv[k];
    float4 x = *reinterpret_cast<const float4*>(Xl + (size_t)v * DD);
    ax += x.x; ay += x.y; az += x.z; aw += x.w;
  }
  float scale = degE[gw] / fmaxf((float)(t - s), 1.0f);
  float4 r;
  r.x = ax * scale; r.y = ay * scale; r.z = az * scale; r.w = aw * scale;
  *reinterpret_cast<float4*>(Xe + (size_t)gw * DD + lane * 4) = r;
}

// ---------------- hop 2: sum-aggregate edges into vertices + norm + alpha-mix ----

__global__ void k_hop2(const float* __restrict__ Xe, const float* __restrict__ X0,
                       const float* __restrict__ degV, const int* __restrict__ offsV,
                       const int* __restrict__ incVe, const float* __restrict__ alpha_p,
                       float* __restrict__ Xi, int N) {
  int gw = (blockIdx.x * blockDim.x + threadIdx.x) >> 6;
  int lane = threadIdx.x & 63;
  if (gw >= N) return;
  int s = offsV[gw], t = offsV[gw + 1];
  float ax = 0.f, ay = 0.f, az = 0.f, aw = 0.f;
  const float* Xel = Xe + lane * 4;
  for (int k = s; k < t; ++k) {
    int e = incVe[k];
    float4 x = *reinterpret_cast<const float4*>(Xel + (size_t)e * DD);
    ax += x.x; ay += x.y; az += x.z; aw += x.w;
  }
  float dv = degV[gw];
  ax *= dv; ay *= dv; az *= dv; aw *= dv;
  // row L2 norm across the 64 lanes (256 features)
  float ss = ax * ax + ay * ay + az * az + aw * aw;
  #pragma unroll
  for (int o = 32; o > 0; o >>= 1) ss += __shfl_down(ss, o);
  ss = __shfl(ss, 0);
  float norm = sqrtf(ss);
  float scl = (norm > 0.f) ? (1.0f / norm) : 0.f;
  float a = alpha_p[0];
  float oma = 1.0f - a;
  float4 x0 = *reinterpret_cast<const float4*>(X0 + (size_t)gw * DD + lane * 4);
  float4 r;
  r.x = oma * (ax * scl) + a * x0.x;
  r.y = oma * (ay * scl) + a * x0.y;
  r.z = oma * (az * scl) + a * x0.z;
  r.w = oma * (aw * scl) + a * x0.w;
  *reinterpret_cast<float4*>(Xi + (size_t)gw * DD + lane * 4) = r;
}

// ---------------- final: out = (1-beta)*Xi + beta*(Xi @ W), in-place on d_out ----
// block = 64 rows x all 256 cols; each block owns its rows exclusively -> in-place safe

__global__ __launch_bounds__(256) void k_gemm(float* XiOut, const float* __restrict__ W,
                                              const float* __restrict__ beta_p, int nrows) {
  __shared__ float As[16][68];    // As[kk][row], pad 68 -> 2-way-free staging writes
  __shared__ float Bs[16][256];   // Bs[kk][col]
  int tid = threadIdx.x;
  int tx = tid & 15;              // 16 col groups
  int ty = tid >> 4;              // 16 row groups (4 rows each)
  int row0 = blockIdx.x * 64;

  float acc[4][16];
  #pragma unroll
  for (int i = 0; i < 4; ++i)
    #pragma unroll
    for (int j = 0; j < 16; ++j) acc[i][j] = 0.f;

  int ar = tid >> 2;              // 0..63 row
  int akk = (tid & 3) * 4;        // k sub-offset
  int bc = tid & 63;              // float4 col index
  int bkk = tid >> 6;             // 0..3

  for (int k0 = 0; k0 < 256; k0 += 16) {
    // stage A tile (64 rows x 16 k), transposed into As[kk][row]
    {
      int grow = row0 + ar;
      float4 av;
      if (grow < nrows)
        av = *reinterpret_cast<const float4*>(XiOut + (size_t)grow * 256 + k0 + akk);
      else { av.x = av.y = av.z = av.w = 0.f; }
      As[akk + 0][ar] = av.x;
      As[akk + 1][ar] = av.y;
      As[akk + 2][ar] = av.z;
      As[akk + 3][ar] = av.w;
    }
    // stage B tile (16 k x 256 cols) of W
    #pragma unroll
    for (int p = 0; p < 4; ++p) {
      int kk = p * 4 + bkk;
      *reinterpret_cast<float4*>(&Bs[kk][bc * 4]) =
          *reinterpret_cast<const float4*>(W + (size_t)(k0 + kk) * 256 + bc * 4);
    }
    __syncthreads();
    #pragma unroll
    for (int kk = 0; kk < 16; ++kk) {
      float4 a4 = *reinterpret_cast<const float4*>(&As[kk][ty * 4]);
      float av_[4] = {a4.x, a4.y, a4.z, a4.w};
      #pragma unroll
      for (int q = 0; q < 4; ++q) {
        float4 b4 = *reinterpret_cast<const float4*>(&Bs[kk][q * 64 + tx * 4]);
        float bv_[4] = {b4.x, b4.y, b4.z, b4.w};
        #pragma unroll
        for (int i = 0; i < 4; ++i)
          #pragma unroll
          for (int j = 0; j < 4; ++j)
            acc[i][q * 4 + j] = fmaf(av_[i], bv_[j], acc[i][q * 4 + j]);
      }
    }
    __syncthreads();
  }

  float b = beta_p[0], ob = 1.0f - b;
  #pragma unroll
  for (int i = 0; i < 4; ++i) {
    int r = row0 + ty * 4 + i;
    if (r >= nrows) continue;
    #pragma unroll
    for (int q = 0; q < 4; ++q) {
      int c = q * 64 + tx * 4;
      float4 xi = *reinterpret_cast<const float4*>(XiOut + (size_t)r * 256 + c);
      float4 o;
      o.x = ob * xi.x + b * acc[i][q * 4 + 0];
      o.y = ob * xi.y + b * acc[i][q * 4 + 1];
      o.z = ob * xi.z + b * acc[i][q * 4 + 2];
      o.w = ob * xi.w + b * acc[i][q * 4 + 3];
      *reinterpret_cast<float4*>(XiOut + (size_t)r * 256 + c) = o;
    }
  }
}

// ---------------- launch ----------------

extern "C" void kernel_launch(void* const* d_in, const int* in_sizes, int n_in,
                              void* d_out, int out_size, void* d_ws, size_t ws_size,
                              hipStream_t stream) {
  const float* X     = (const float*)d_in[0];
  const float* X0    = (const float*)d_in[1];
  const float* W     = (const float*)d_in[2];
  const float* degV  = (const float*)d_in[3];
  const float* degE  = (const float*)d_in[4];
  const int*   vertex= (const int*)d_in[5];
  const int*   edges = (const int*)d_in[6];
  const float* alpha = (const float*)d_in[7];
  const float* beta  = (const float*)d_in[8];

  const int N   = in_sizes[3];   // degV has N elements
  const int M   = in_sizes[4];   // degE has M elements
  const int NNZ = in_sizes[5];

  int* w = (int*)d_ws;
  int* cntE  = w; w += M;
  int* cntV  = w; w += N;        // contiguous with cntE for one memset
  int* offsE = w; w += M + 1;
  int* offsV = w; w += N + 1;
  int* curE  = w; w += M;
  int* curV  = w; w += N;
  int* incEv = w; w += NNZ;
  int* incVe = w; w += NNZ;
  uintptr_t p = (uintptr_t)w;
  p = (p + 15) & ~(uintptr_t)15;
  float* Xe = (float*)p;                 // M * 256 floats
  float* Xi = (float*)d_out;             // N * 256 floats (in-place with final GEMM)

  hipMemsetAsync(cntE, 0, (size_t)(M + N) * sizeof(int), stream);

  int nb = (NNZ + 255) / 256;
  k_count<<<nb, 256, 0, stream>>>(vertex, edges, cntV, cntE, NNZ);
  k_scan<<<1, 1024, 0, stream>>>(cntE, offsE, curE, M);
  k_scan<<<1, 1024, 0, stream>>>(cntV, offsV, curV, N);
  k_fill<<<nb, 256, 0, stream>>>(vertex, edges, curE, curV, incEv, incVe, NNZ);

  k_hop1<<<(M + 3) / 4, 256, 0, stream>>>(X, degE, offsE, incEv, Xe, M);
  k_hop2<<<(N + 3) / 4, 256, 0, stream>>>(Xe, X0, degV, offsV, incVe, alpha, Xi, N);
  k_gemm<<<(N + 63) / 64, 256, 0, stream>>>(Xi, W, beta, N);
}

// Round 2
// 327.951 us; speedup vs baseline: 1.4106x; 1.4106x over previous
//
#include <hip/hip_runtime.h>
#include <cstdint>

static constexpr int DD = 256;   // feature dim (fixed by problem)
static constexpr int SNB = 64;   // scan blocks per array

// ---------------- CSR build ----------------

__global__ void k_count(const int* __restrict__ vertex, const int* __restrict__ edges,
                        int* __restrict__ cntV, int* __restrict__ cntE, int nnz) {
  int i = blockIdx.x * blockDim.x + threadIdx.x;
  if (i < nnz) {
    atomicAdd(&cntV[vertex[i]], 1);
    atomicAdd(&cntE[edges[i]], 1);
  }
}

__device__ inline int wave_incl_scan(int v, int lane) {
  #pragma unroll
  for (int o = 1; o < 64; o <<= 1) {
    int u = __shfl_up(v, o);
    if (lane >= o) v += u;
  }
  return v;
}

// Phase 1: per-chunk sums for both arrays. blocks 0..63 -> E, 64..127 -> V.
__global__ __launch_bounds__(256) void k_bsum(const int* __restrict__ cntE,
                                              const int* __restrict__ cntV,
                                              int* __restrict__ bsum, int M, int N) {
  int arr = blockIdx.x >> 6;
  int b = blockIdx.x & 63;
  const int* cnt = arr ? cntV : cntE;
  int n = arr ? N : M;
  int chunk = (((n + SNB - 1) / SNB) + 3) & ~3;
  int lo = b * chunk, hi = min(lo + chunk, n);
  int s = 0;
  for (int i = lo + (int)threadIdx.x; i < hi; i += 256) s += cnt[i];
  #pragma unroll
  for (int o = 32; o; o >>= 1) s += __shfl_down(s, o);
  __shared__ int sh[4];
  if ((threadIdx.x & 63) == 0) sh[threadIdx.x >> 6] = s;
  __syncthreads();
  if (threadIdx.x == 0) bsum[blockIdx.x] = sh[0] + sh[1] + sh[2] + sh[3];
}

// Phase 2: scan the 128 block sums (wave 0 = E, wave 1 = V); write totals.
__global__ __launch_bounds__(128) void k_bscan(const int* __restrict__ bsum,
                                               int* __restrict__ bpre,
                                               int* __restrict__ offsE, int* __restrict__ offsV,
                                               int M, int N) {
  int t = threadIdx.x;
  int lane = t & 63;
  int v = bsum[t];
  int inc = wave_incl_scan(v, lane);
  bpre[t] = inc - v;
  if (lane == 63) {
    if (t < 64) offsE[M] = inc;
    else        offsV[N] = inc;
  }
}

// Phase 3: per-chunk exclusive scan + global base, write offs & cursor (int4).
__global__ __launch_bounds__(256) void k_woffs(const int* __restrict__ cntE,
                                               const int* __restrict__ cntV,
                                               const int* __restrict__ bpre,
                                               int* __restrict__ offsE, int* __restrict__ curE,
                                               int* __restrict__ offsV, int* __restrict__ curV,
                                               int M, int N) {
  int arr = blockIdx.x >> 6;
  int b = blockIdx.x & 63;
  const int* cnt = arr ? cntV : cntE;
  int* offs = arr ? offsV : offsE;
  int* cur  = arr ? curV  : curE;
  int n = arr ? N : M;
  int chunk = (((n + SNB - 1) / SNB) + 3) & ~3;   // chunk <= 1024 for n <= 65536
  int lo = b * chunk, hi = min(lo + chunk, n);
  if (lo >= n) return;
  int base = bpre[blockIdx.x];

  int idx = lo + (int)threadIdx.x * 4;
  int c0 = 0, c1 = 0, c2 = 0, c3 = 0;
  if (idx + 3 < hi) {
    int4 c = *reinterpret_cast<const int4*>(cnt + idx);
    c0 = c.x; c1 = c.y; c2 = c.z; c3 = c.w;
  } else if (idx < hi) {
    c0 = cnt[idx];
    if (idx + 1 < hi) c1 = cnt[idx + 1];
    if (idx + 2 < hi) c2 = cnt[idx + 2];
  }
  int tsum = c0 + c1 + c2 + c3;
  int lane = threadIdx.x & 63, wid = threadIdx.x >> 6;
  int winc = wave_incl_scan(tsum, lane);
  __shared__ int wtot[4];
  if (lane == 63) wtot[wid] = winc;
  __syncthreads();
  int wbase = 0;
  #pragma unroll
  for (int q = 0; q < 4; ++q) wbase += (q < wid) ? wtot[q] : 0;
  int excl = base + wbase + winc - tsum;
  int o0 = excl, o1 = o0 + c0, o2 = o1 + c1, o3 = o2 + c2;
  if (idx + 3 < hi) {
    *reinterpret_cast<int4*>(offs + idx) = make_int4(o0, o1, o2, o3);
    *reinterpret_cast<int4*>(cur + idx)  = make_int4(o0, o1, o2, o3);
  } else if (idx < hi) {
    offs[idx] = o0; cur[idx] = o0;
    if (idx + 1 < hi) { offs[idx + 1] = o1; cur[idx + 1] = o1; }
    if (idx + 2 < hi) { offs[idx + 2] = o2; cur[idx + 2] = o2; }
  }
}

__global__ void k_fill(const int* __restrict__ vertex, const int* __restrict__ edges,
                       int* __restrict__ curE, int* __restrict__ curV,
                       int* __restrict__ incEv, int* __restrict__ incVe, int nnz) {
  int i = blockIdx.x * blockDim.x + threadIdx.x;
  if (i < nnz) {
    int v = vertex[i], e = edges[i];
    int pe = atomicAdd(&curE[e], 1);
    incEv[pe] = v;              // per-edge list of member vertices
    int pv = atomicAdd(&curV[v], 1);
    incVe[pv] = e;              // per-vertex list of incident edges
  }
}

// ---------------- hop 1: mean-aggregate vertices into edges ----------------

__global__ void k_hop1(const float* __restrict__ X, const float* __restrict__ degE,
                       const int* __restrict__ offsE, const int* __restrict__ incEv,
                       float* __restrict__ Xe, int M) {
  int gw = (blockIdx.x * blockDim.x + threadIdx.x) >> 6;
  int lane = threadIdx.x & 63;
  if (gw >= M) return;
  int s = offsE[gw], t = offsE[gw + 1];
  float ax = 0.f, ay = 0.f, az = 0.f, aw = 0.f;
  const float* Xl = X + lane * 4;
  for (int k = s; k < t; ++k) {
    int v = incEv[k];
    float4 x = *reinterpret_cast<const float4*>(Xl + (size_t)v * DD);
    ax += x.x; ay += x.y; az += x.z; aw += x.w;
  }
  float scale = degE[gw] / fmaxf((float)(t - s), 1.0f);
  float4 r;
  r.x = ax * scale; r.y = ay * scale; r.z = az * scale; r.w = aw * scale;
  *reinterpret_cast<float4*>(Xe + (size_t)gw * DD + lane * 4) = r;
}

// ---------------- hop 2: sum-aggregate edges into vertices + norm + alpha-mix ----

__global__ void k_hop2(const float* __restrict__ Xe, const float* __restrict__ X0,
                       const float* __restrict__ degV, const int* __restrict__ offsV,
                       const int* __restrict__ incVe, const float* __restrict__ alpha_p,
                       float* __restrict__ Xi, int N) {
  int gw = (blockIdx.x * blockDim.x + threadIdx.x) >> 6;
  int lane = threadIdx.x & 63;
  if (gw >= N) return;
  int s = offsV[gw], t = offsV[gw + 1];
  float ax = 0.f, ay = 0.f, az = 0.f, aw = 0.f;
  const float* Xel = Xe + lane * 4;
  for (int k = s; k < t; ++k) {
    int e = incVe[k];
    float4 x = *reinterpret_cast<const float4*>(Xel + (size_t)e * DD);
    ax += x.x; ay += x.y; az += x.z; aw += x.w;
  }
  float dv = degV[gw];
  ax *= dv; ay *= dv; az *= dv; aw *= dv;
  float ss = ax * ax + ay * ay + az * az + aw * aw;
  #pragma unroll
  for (int o = 32; o > 0; o >>= 1) ss += __shfl_down(ss, o);
  ss = __shfl(ss, 0);
  float norm = sqrtf(ss);
  float scl = (norm > 0.f) ? (1.0f / norm) : 0.f;
  float a = alpha_p[0];
  float oma = 1.0f - a;
  float4 x0 = *reinterpret_cast<const float4*>(X0 + (size_t)gw * DD + lane * 4);
  float4 r;
  r.x = oma * (ax * scl) + a * x0.x;
  r.y = oma * (ay * scl) + a * x0.y;
  r.z = oma * (az * scl) + a * x0.z;
  r.w = oma * (aw * scl) + a * x0.w;
  *reinterpret_cast<float4*>(Xi + (size_t)gw * DD + lane * 4) = r;
}

// ---------------- final: out = (1-beta)*Xi + beta*(Xi @ W), in-place on d_out ----

__global__ __launch_bounds__(256) void k_gemm(float* XiOut, const float* __restrict__ W,
                                              const float* __restrict__ beta_p, int nrows) {
  __shared__ float As[16][68];
  __shared__ float Bs[16][256];
  int tid = threadIdx.x;
  int tx = tid & 15;
  int ty = tid >> 4;
  int row0 = blockIdx.x * 64;

  float acc[4][16];
  #pragma unroll
  for (int i = 0; i < 4; ++i)
    #pragma unroll
    for (int j = 0; j < 16; ++j) acc[i][j] = 0.f;

  int ar = tid >> 2;
  int akk = (tid & 3) * 4;
  int bc = tid & 63;
  int bkk = tid >> 6;

  for (int k0 = 0; k0 < 256; k0 += 16) {
    {
      int grow = row0 + ar;
      float4 av;
      if (grow < nrows)
        av = *reinterpret_cast<const float4*>(XiOut + (size_t)grow * 256 + k0 + akk);
      else { av.x = av.y = av.z = av.w = 0.f; }
      As[akk + 0][ar] = av.x;
      As[akk + 1][ar] = av.y;
      As[akk + 2][ar] = av.z;
      As[akk + 3][ar] = av.w;
    }
    #pragma unroll
    for (int p = 0; p < 4; ++p) {
      int kk = p * 4 + bkk;
      *reinterpret_cast<float4*>(&Bs[kk][bc * 4]) =
          *reinterpret_cast<const float4*>(W + (size_t)(k0 + kk) * 256 + bc * 4);
    }
    __syncthreads();
    #pragma unroll
    for (int kk = 0; kk < 16; ++kk) {
      float4 a4 = *reinterpret_cast<const float4*>(&As[kk][ty * 4]);
      float av_[4] = {a4.x, a4.y, a4.z, a4.w};
      #pragma unroll
      for (int q = 0; q < 4; ++q) {
        float4 b4 = *reinterpret_cast<const float4*>(&Bs[kk][q * 64 + tx * 4]);
        float bv_[4] = {b4.x, b4.y, b4.z, b4.w};
        #pragma unroll
        for (int i = 0; i < 4; ++i)
          #pragma unroll
          for (int j = 0; j < 4; ++j)
            acc[i][q * 4 + j] = fmaf(av_[i], bv_[j], acc[i][q * 4 + j]);
      }
    }
    __syncthreads();
  }

  float b = beta_p[0], ob = 1.0f - b;
  #pragma unroll
  for (int i = 0; i < 4; ++i) {
    int r = row0 + ty * 4 + i;
    if (r >= nrows) continue;
    #pragma unroll
    for (int q = 0; q < 4; ++q) {
      int c = q * 64 + tx * 4;
      float4 xi = *reinterpret_cast<const float4*>(XiOut + (size_t)r * 256 + c);
      float4 o;
      o.x = ob * xi.x + b * acc[i][q * 4 + 0];
      o.y = ob * xi.y + b * acc[i][q * 4 + 1];
      o.z = ob * xi.z + b * acc[i][q * 4 + 2];
      o.w = ob * xi.w + b * acc[i][q * 4 + 3];
      *reinterpret_cast<float4*>(XiOut + (size_t)r * 256 + c) = o;
    }
  }
}

// ---------------- launch ----------------

extern "C" void kernel_launch(void* const* d_in, const int* in_sizes, int n_in,
                              void* d_out, int out_size, void* d_ws, size_t ws_size,
                              hipStream_t stream) {
  const float* X     = (const float*)d_in[0];
  const float* X0    = (const float*)d_in[1];
  const float* W     = (const float*)d_in[2];
  const float* degV  = (const float*)d_in[3];
  const float* degE  = (const float*)d_in[4];
  const int*   vertex= (const int*)d_in[5];
  const int*   edges = (const int*)d_in[6];
  const float* alpha = (const float*)d_in[7];
  const float* beta  = (const float*)d_in[8];

  const int N   = in_sizes[3];   // degV has N elements
  const int M   = in_sizes[4];   // degE has M elements
  const int NNZ = in_sizes[5];

  auto r4 = [](int x) { return (x + 3) & ~3; };
  const int Mr = r4(M), Nr = r4(N);

  int* w = (int*)d_ws;
  int* cntE  = w; w += Mr;
  int* cntV  = w; w += Nr;        // contiguous with cntE for one memset
  int* offsE = w; w += r4(M + 1);
  int* offsV = w; w += r4(N + 1);
  int* curE  = w; w += Mr;
  int* curV  = w; w += Nr;
  int* bsum  = w; w += 128;
  int* bpre  = w; w += 128;
  int* incEv = w; w += r4(NNZ);
  int* incVe = w; w += r4(NNZ);
  uintptr_t p = (uintptr_t)w;
  p = (p + 15) & ~(uintptr_t)15;
  float* Xe = (float*)p;                 // M * 256 floats
  float* Xi = (float*)d_out;             // N * 256 floats (in-place with final GEMM)

  hipMemsetAsync(cntE, 0, (size_t)(Mr + Nr) * sizeof(int), stream);

  int nb = (NNZ + 255) / 256;
  k_count<<<nb, 256, 0, stream>>>(vertex, edges, cntV, cntE, NNZ);
  k_bsum <<<2 * SNB, 256, 0, stream>>>(cntE, cntV, bsum, M, N);
  k_bscan<<<1, 128, 0, stream>>>(bsum, bpre, offsE, offsV, M, N);
  k_woffs<<<2 * SNB, 256, 0, stream>>>(cntE, cntV, bpre, offsE, curE, offsV, curV, M, N);
  k_fill <<<nb, 256, 0, stream>>>(vertex, edges, curE, curV, incEv, incVe, NNZ);

  k_hop1<<<(M + 3) / 4, 256, 0, stream>>>(X, degE, offsE, incEv, Xe, M);
  k_hop2<<<(N + 3) / 4, 256, 0, stream>>>(Xe, X0, degV, offsV, incVe, alpha, Xi, N);
  k_gemm<<<(N + 63) / 64, 256, 0, stream>>>(Xi, W, beta, N);
}

// Round 4
// 288.534 us; speedup vs baseline: 1.6033x; 1.1366x over previous
//
#include <hip/hip_runtime.h>
#include <cstdint>

static constexpr int DD = 256;   // feature dim (fixed by problem)
static constexpr int SNB = 64;   // scan blocks per array

typedef unsigned short ushort_t;
typedef __attribute__((ext_vector_type(8))) short short8v;   // 8 bf16 (4 VGPRs)
typedef __attribute__((ext_vector_type(4))) float f32x4;

static __device__ inline ushort_t f2bf(float f) {     // RNE f32->bf16 (no NaN in data)
  uint32_t u = __builtin_bit_cast(uint32_t, f);
  uint32_t r = (u + 0x7fffu + ((u >> 16) & 1u)) >> 16;
  return (ushort_t)r;
}

// ---------------- CSR build ----------------

__global__ void k_count(const int* __restrict__ vertex, const int* __restrict__ edges,
                        int* __restrict__ cntV, int* __restrict__ cntE, int nnz) {
  int i = blockIdx.x * blockDim.x + threadIdx.x;
  if (i < nnz) {
    atomicAdd(&cntV[vertex[i]], 1);
    atomicAdd(&cntE[edges[i]], 1);
  }
}

__device__ inline int wave_incl_scan(int v, int lane) {
  #pragma unroll
  for (int o = 1; o < 64; o <<= 1) {
    int u = __shfl_up(v, o);
    if (lane >= o) v += u;
  }
  return v;
}

// Phase 1: per-chunk sums for both arrays. blocks 0..63 -> E, 64..127 -> V.
__global__ __launch_bounds__(256) void k_bsum(const int* __restrict__ cntE,
                                              const int* __restrict__ cntV,
                                              int* __restrict__ bsum, int M, int N) {
  int arr = blockIdx.x >> 6;
  int b = blockIdx.x & 63;
  const int* cnt = arr ? cntV : cntE;
  int n = arr ? N : M;
  int chunk = (((n + SNB - 1) / SNB) + 3) & ~3;
  int lo = b * chunk, hi = min(lo + chunk, n);
  int s = 0;
  for (int i = lo + (int)threadIdx.x; i < hi; i += 256) s += cnt[i];
  #pragma unroll
  for (int o = 32; o; o >>= 1) s += __shfl_down(s, o);
  __shared__ int sh[4];
  if ((threadIdx.x & 63) == 0) sh[threadIdx.x >> 6] = s;
  __syncthreads();
  if (threadIdx.x == 0) bsum[blockIdx.x] = sh[0] + sh[1] + sh[2] + sh[3];
}

// Phase 2: scan the 128 block sums (wave 0 = E, wave 1 = V); write totals.
__global__ __launch_bounds__(128) void k_bscan(const int* __restrict__ bsum,
                                               int* __restrict__ bpre,
                                               int* __restrict__ offsE, int* __restrict__ offsV,
                                               int M, int N) {
  int t = threadIdx.x;
  int lane = t & 63;
  int v = bsum[t];
  int inc = wave_incl_scan(v, lane);
  bpre[t] = inc - v;
  if (lane == 63) {
    if (t < 64) offsE[M] = inc;
    else        offsV[N] = inc;
  }
}

// Phase 3: per-chunk exclusive scan + global base, write offs & cursor (int4).
__global__ __launch_bounds__(256) void k_woffs(const int* __restrict__ cntE,
                                               const int* __restrict__ cntV,
                                               const int* __restrict__ bpre,
                                               int* __restrict__ offsE, int* __restrict__ curE,
                                               int* __restrict__ offsV, int* __restrict__ curV,
                                               int M, int N) {
  int arr = blockIdx.x >> 6;
  int b = blockIdx.x & 63;
  const int* cnt = arr ? cntV : cntE;
  int* offs = arr ? offsV : offsE;
  int* cur  = arr ? curV  : curE;
  int n = arr ? N : M;
  int chunk = (((n + SNB - 1) / SNB) + 3) & ~3;
  int lo = b * chunk, hi = min(lo + chunk, n);
  if (lo >= n) return;
  int base = bpre[blockIdx.x];

  int idx = lo + (int)threadIdx.x * 4;
  int c0 = 0, c1 = 0, c2 = 0, c3 = 0;
  if (idx + 3 < hi) {
    int4 c = *reinterpret_cast<const int4*>(cnt + idx);
    c0 = c.x; c1 = c.y; c2 = c.z; c3 = c.w;
  } else if (idx < hi) {
    c0 = cnt[idx];
    if (idx + 1 < hi) c1 = cnt[idx + 1];
    if (idx + 2 < hi) c2 = cnt[idx + 2];
  }
  int tsum = c0 + c1 + c2 + c3;
  int lane = threadIdx.x & 63, wid = threadIdx.x >> 6;
  int winc = wave_incl_scan(tsum, lane);
  __shared__ int wtot[4];
  if (lane == 63) wtot[wid] = winc;
  __syncthreads();
  int wbase = 0;
  #pragma unroll
  for (int q = 0; q < 4; ++q) wbase += (q < wid) ? wtot[q] : 0;
  int excl = base + wbase + winc - tsum;
  int o0 = excl, o1 = o0 + c0, o2 = o1 + c1, o3 = o2 + c2;
  if (idx + 3 < hi) {
    *reinterpret_cast<int4*>(offs + idx) = make_int4(o0, o1, o2, o3);
    *reinterpret_cast<int4*>(cur + idx)  = make_int4(o0, o1, o2, o3);
  } else if (idx < hi) {
    offs[idx] = o0; cur[idx] = o0;
    if (idx + 1 < hi) { offs[idx + 1] = o1; cur[idx + 1] = o1; }
    if (idx + 2 < hi) { offs[idx + 2] = o2; cur[idx + 2] = o2; }
  }
}

__global__ void k_fill(const int* __restrict__ vertex, const int* __restrict__ edges,
                       int* __restrict__ curE, int* __restrict__ curV,
                       int* __restrict__ incEv, int* __restrict__ incVe, int nnz) {
  int i = blockIdx.x * blockDim.x + threadIdx.x;
  if (i < nnz) {
    int v = vertex[i], e = edges[i];
    int pe = atomicAdd(&curE[e], 1);
    incEv[pe] = v;
    int pv = atomicAdd(&curV[v], 1);
    incVe[pv] = e;
  }
}

// ---------------- hop 1: mean-aggregate vertices into edges ----------------

__global__ void k_hop1(const float* __restrict__ X, const float* __restrict__ degE,
                       const int* __restrict__ offsE, const int* __restrict__ incEv,
                       float* __restrict__ Xe, int M) {
  int gw = (blockIdx.x * blockDim.x + threadIdx.x) >> 6;
  int lane = threadIdx.x & 63;
  if (gw >= M) return;
  int s = offsE[gw], t = offsE[gw + 1];
  float ax = 0.f, ay = 0.f, az = 0.f, aw = 0.f;
  const float* Xl = X + lane * 4;
  for (int k = s; k < t; ++k) {
    int v = incEv[k];
    float4 x = *reinterpret_cast<const float4*>(Xl + (size_t)v * DD);
    ax += x.x; ay += x.y; az += x.z; aw += x.w;
  }
  float scale = degE[gw] / fmaxf((float)(t - s), 1.0f);
  float4 r;
  r.x = ax * scale; r.y = ay * scale; r.z = az * scale; r.w = aw * scale;
  *reinterpret_cast<float4*>(Xe + (size_t)gw * DD + lane * 4) = r;
}

// ---------------- hop 2: sum-aggregate edges into vertices + norm + alpha-mix ----

__global__ void k_hop2(const float* __restrict__ Xe, const float* __restrict__ X0,
                       const float* __restrict__ degV, const int* __restrict__ offsV,
                       const int* __restrict__ incVe, const float* __restrict__ alpha_p,
                       float* __restrict__ Xi, int N) {
  int gw = (blockIdx.x * blockDim.x + threadIdx.x) >> 6;
  int lane = threadIdx.x & 63;
  if (gw >= N) return;
  int s = offsV[gw], t = offsV[gw + 1];
  float ax = 0.f, ay = 0.f, az = 0.f, aw = 0.f;
  const float* Xel = Xe + lane * 4;
  for (int k = s; k < t; ++k) {
    int e = incVe[k];
    float4 x = *reinterpret_cast<const float4*>(Xel + (size_t)e * DD);
    ax += x.x; ay += x.y; az += x.z; aw += x.w;
  }
  float dv = degV[gw];
  ax *= dv; ay *= dv; az *= dv; aw *= dv;
  float ss = ax * ax + ay * ay + az * az + aw * aw;
  #pragma unroll
  for (int o = 32; o > 0; o >>= 1) ss += __shfl_down(ss, o);
  ss = __shfl(ss, 0);
  float norm = sqrtf(ss);
  float scl = (norm > 0.f) ? (1.0f / norm) : 0.f;
  float a = alpha_p[0];
  float oma = 1.0f - a;
  float4 x0 = *reinterpret_cast<const float4*>(X0 + (size_t)gw * DD + lane * 4);
  float4 r;
  r.x = oma * (ax * scl) + a * x0.x;
  r.y = oma * (ay * scl) + a * x0.y;
  r.z = oma * (az * scl) + a * x0.z;
  r.w = oma * (aw * scl) + a * x0.w;
  *reinterpret_cast<float4*>(Xi + (size_t)gw * DD + lane * 4) = r;
}

// ---------------- W precompute: Wt[col][k] = bf16(W[k][col]) ----------------
// Wt OVERLAYS curE/curV (dead after k_fill) -> ws footprint identical to the
// proven-safe R2 layout. Launched after k_fill.

__global__ __launch_bounds__(256) void k_wcvt(const float* __restrict__ W,
                                              ushort_t* __restrict__ Wt) {
  int t = blockIdx.x * 256 + threadIdx.x;     // 65536 threads
  int k = t >> 8, c = t & 255;
  Wt[c * 256 + k] = f2bf(W[t]);               // coalesced read of W[k][c]
}

// ---------------- final: out = (1-beta)*Xi + beta*(Xi @ W), bf16 MFMA, in-place ----
// block = 64 rows x 256 cols, 4 waves, each wave 16 rows x 256 cols (16 C-fragments).

__global__ __launch_bounds__(256) void k_gemm_mfma(float* XiOut,
                                                   const ushort_t* __restrict__ Wt,
                                                   const float* __restrict__ beta_p,
                                                   int nrows) {
  __shared__ ushort_t A_lds[64][40];     // 5 KB
  __shared__ ushort_t B_lds[256][40];    // 20 KB
  const int tid = threadIdx.x;
  const int lane = tid & 63;
  const int wid = tid >> 6;
  const int l15 = lane & 15;
  const int l4  = lane >> 4;             // 0..3
  const int row0 = blockIdx.x * 64;

  f32x4 acc[16];
  #pragma unroll
  for (int n = 0; n < 16; ++n) acc[n] = (f32x4){0.f, 0.f, 0.f, 0.f};

  for (int k0 = 0; k0 < 256; k0 += 32) {
    // stage A: 64 rows x 32 k (f32 -> bf16)
    #pragma unroll
    for (int p = 0; p < 2; ++p) {
      int flat = p * 256 + tid;          // 0..511
      int row = flat >> 3;               // 0..63
      int c4  = flat & 7;                // float4 index within the 32-k tile
      int grow = row0 + row;
      float4 av = make_float4(0.f, 0.f, 0.f, 0.f);
      if (grow < nrows)
        av = *reinterpret_cast<const float4*>(XiOut + (size_t)grow * 256 + k0 + c4 * 4);
      uint2 pk;
      pk.x = (uint32_t)f2bf(av.x) | ((uint32_t)f2bf(av.y) << 16);
      pk.y = (uint32_t)f2bf(av.z) | ((uint32_t)f2bf(av.w) << 16);
      *reinterpret_cast<uint2*>(&A_lds[row][c4 * 4]) = pk;
    }
    // stage B: 256 cols x 32 k from Wt[col][k] (already bf16)
    {
      const ushort_t* src = Wt + (size_t)tid * 256 + k0;
      #pragma unroll
      for (int p = 0; p < 4; ++p) {
        int4 wv = *reinterpret_cast<const int4*>(src + p * 8);
        *reinterpret_cast<int4*>(&B_lds[tid][p * 8]) = wv;
      }
    }
    __syncthreads();
    short8v a = *reinterpret_cast<const short8v*>(&A_lds[wid * 16 + l15][l4 * 8]);
    #pragma unroll
    for (int n = 0; n < 16; ++n) {
      short8v bfr = *reinterpret_cast<const short8v*>(&B_lds[n * 16 + l15][l4 * 8]);
      acc[n] = __builtin_amdgcn_mfma_f32_16x16x32_bf16(a, bfr, acc[n], 0, 0, 0);
    }
    __syncthreads();
  }

  // epilogue: out = (1-b)*Xi + b*acc  (C/D layout: col = lane&15, row = (lane>>4)*4 + reg)
  float b = beta_p[0], ob = 1.0f - b;
  int rbase = row0 + wid * 16 + l4 * 4;
  #pragma unroll
  for (int n = 0; n < 16; ++n) {
    int col = n * 16 + l15;
    #pragma unroll
    for (int j = 0; j < 4; ++j) {
      int r = rbase + j;
      if (r < nrows) {
        size_t idx = (size_t)r * 256 + col;
        float xi = XiOut[idx];
        XiOut[idx] = ob * xi + b * acc[n][j];
      }
    }
  }
}

// ---------------- launch ----------------

extern "C" void kernel_launch(void* const* d_in, const int* in_sizes, int n_in,
                              void* d_out, int out_size, void* d_ws, size_t ws_size,
                              hipStream_t stream) {
  const float* X     = (const float*)d_in[0];
  const float* X0    = (const float*)d_in[1];
  const float* W     = (const float*)d_in[2];
  const float* degV  = (const float*)d_in[3];
  const float* degE  = (const float*)d_in[4];
  const int*   vertex= (const int*)d_in[5];
  const int*   edges = (const int*)d_in[6];
  const float* alpha = (const float*)d_in[7];
  const float* beta  = (const float*)d_in[8];

  const int N   = in_sizes[3];   // degV has N elements
  const int M   = in_sizes[4];   // degE has M elements
  const int NNZ = in_sizes[5];

  auto r4 = [](int x) { return (x + 3) & ~3; };
  const int Mr = r4(M), Nr = r4(N);

  int* w = (int*)d_ws;
  int* cntE  = w; w += Mr;
  int* cntV  = w; w += Nr;        // contiguous with cntE for one memset
  int* offsE = w; w += r4(M + 1);
  int* offsV = w; w += r4(N + 1);
  int* curE  = w; w += Mr;        // dead after k_fill -> reused for Wt
  int* curV  = w; w += Nr;        // dead after k_fill -> reused for Wt
  int* bsum  = w; w += 128;
  int* bpre  = w; w += 128;
  int* incEv = w; w += r4(NNZ);
  int* incVe = w; w += r4(NNZ);
  uintptr_t p = (uintptr_t)w;
  p = (p + 15) & ~(uintptr_t)15;
  float* Xe = (float*)p;                 // M * 256 floats  (ws end == proven R2 footprint)
  float* Xi = (float*)d_out;             // N * 256 floats (in-place with final GEMM)

  // Wt overlays curE/curV (128 KB < 280 KB, 16B-aligned); valid only after k_fill.
  ushort_t* Wt = (ushort_t*)curE;

  hipMemsetAsync(cntE, 0, (size_t)(Mr + Nr) * sizeof(int), stream);

  int nb = (NNZ + 255) / 256;
  k_count<<<nb, 256, 0, stream>>>(vertex, edges, cntV, cntE, NNZ);
  k_bsum <<<2 * SNB, 256, 0, stream>>>(cntE, cntV, bsum, M, N);
  k_bscan<<<1, 128, 0, stream>>>(bsum, bpre, offsE, offsV, M, N);
  k_woffs<<<2 * SNB, 256, 0, stream>>>(cntE, cntV, bpre, offsE, curE, offsV, curV, M, N);
  k_fill <<<nb, 256, 0, stream>>>(vertex, edges, curE, curV, incEv, incVe, NNZ);
  k_wcvt <<<256, 256, 0, stream>>>(W, Wt);    // after k_fill: cursors dead

  k_hop1<<<(M + 3) / 4, 256, 0, stream>>>(X, degE, offsE, incEv, Xe, M);
  k_hop2<<<(N + 3) / 4, 256, 0, stream>>>(Xe, X0, degV, offsV, incVe, alpha, Xi, N);
  k_gemm_mfma<<<(N + 63) / 64, 256, 0, stream>>>(Xi, Wt, beta, N);
}

// Round 5
// 275.616 us; speedup vs baseline: 1.6784x; 1.0469x over previous
//
#include <hip/hip_runtime.h>
#include <cstdint>

static constexpr int DD = 256;   // feature dim (fixed by problem)
static constexpr int SNB = 64;   // scan blocks per array

typedef unsigned short ushort_t;
typedef __attribute__((ext_vector_type(8))) short short8v;   // 8 bf16 (4 VGPRs)
typedef __attribute__((ext_vector_type(4))) float f32x4;

static __device__ inline ushort_t f2bf(float f) {     // RNE f32->bf16 (no NaN in data)
  uint32_t u = __builtin_bit_cast(uint32_t, f);
  uint32_t r = (u + 0x7fffu + ((u >> 16) & 1u)) >> 16;
  return (ushort_t)r;
}
static __device__ inline float bf2f(ushort_t u) {
  return __builtin_bit_cast(float, (uint32_t)u << 16);
}

// ---------------- CSR build ----------------

__global__ void k_count(const int* __restrict__ vertex, const int* __restrict__ edges,
                        int* __restrict__ cntV, int* __restrict__ cntE, int nnz) {
  int i = blockIdx.x * blockDim.x + threadIdx.x;
  if (i < nnz) {
    atomicAdd(&cntV[vertex[i]], 1);
    atomicAdd(&cntE[edges[i]], 1);
  }
}

__device__ inline int wave_incl_scan(int v, int lane) {
  #pragma unroll
  for (int o = 1; o < 64; o <<= 1) {
    int u = __shfl_up(v, o);
    if (lane >= o) v += u;
  }
  return v;
}

// Phase 1: per-chunk sums for both arrays. blocks 0..63 -> E, 64..127 -> V.
__global__ __launch_bounds__(256) void k_bsum(const int* __restrict__ cntE,
                                              const int* __restrict__ cntV,
                                              int* __restrict__ bsum, int M, int N) {
  int arr = blockIdx.x >> 6;
  int b = blockIdx.x & 63;
  const int* cnt = arr ? cntV : cntE;
  int n = arr ? N : M;
  int chunk = (((n + SNB - 1) / SNB) + 3) & ~3;
  int lo = b * chunk, hi = min(lo + chunk, n);
  int s = 0;
  for (int i = lo + (int)threadIdx.x; i < hi; i += 256) s += cnt[i];
  #pragma unroll
  for (int o = 32; o; o >>= 1) s += __shfl_down(s, o);
  __shared__ int sh[4];
  if ((threadIdx.x & 63) == 0) sh[threadIdx.x >> 6] = s;
  __syncthreads();
  if (threadIdx.x == 0) bsum[blockIdx.x] = sh[0] + sh[1] + sh[2] + sh[3];
}

// Phase 2: scan the 128 block sums (wave 0 = E, wave 1 = V); write totals.
__global__ __launch_bounds__(128) void k_bscan(const int* __restrict__ bsum,
                                               int* __restrict__ bpre,
                                               int* __restrict__ offsE, int* __restrict__ offsV,
                                               int M, int N) {
  int t = threadIdx.x;
  int lane = t & 63;
  int v = bsum[t];
  int inc = wave_incl_scan(v, lane);
  bpre[t] = inc - v;
  if (lane == 63) {
    if (t < 64) offsE[M] = inc;
    else        offsV[N] = inc;
  }
}

// Phase 3: per-chunk exclusive scan + global base, write offs & cursor (int4).
__global__ __launch_bounds__(256) void k_woffs(const int* __restrict__ cntE,
                                               const int* __restrict__ cntV,
                                               const int* __restrict__ bpre,
                                               int* __restrict__ offsE, int* __restrict__ curE,
                                               int* __restrict__ offsV, int* __restrict__ curV,
                                               int M, int N) {
  int arr = blockIdx.x >> 6;
  int b = blockIdx.x & 63;
  const int* cnt = arr ? cntV : cntE;
  int* offs = arr ? offsV : offsE;
  int* cur  = arr ? curV  : curE;
  int n = arr ? N : M;
  int chunk = (((n + SNB - 1) / SNB) + 3) & ~3;
  int lo = b * chunk, hi = min(lo + chunk, n);
  if (lo >= n) return;
  int base = bpre[blockIdx.x];

  int idx = lo + (int)threadIdx.x * 4;
  int c0 = 0, c1 = 0, c2 = 0, c3 = 0;
  if (idx + 3 < hi) {
    int4 c = *reinterpret_cast<const int4*>(cnt + idx);
    c0 = c.x; c1 = c.y; c2 = c.z; c3 = c.w;
  } else if (idx < hi) {
    c0 = cnt[idx];
    if (idx + 1 < hi) c1 = cnt[idx + 1];
    if (idx + 2 < hi) c2 = cnt[idx + 2];
  }
  int tsum = c0 + c1 + c2 + c3;
  int lane = threadIdx.x & 63, wid = threadIdx.x >> 6;
  int winc = wave_incl_scan(tsum, lane);
  __shared__ int wtot[4];
  if (lane == 63) wtot[wid] = winc;
  __syncthreads();
  int wbase = 0;
  #pragma unroll
  for (int q = 0; q < 4; ++q) wbase += (q < wid) ? wtot[q] : 0;
  int excl = base + wbase + winc - tsum;
  int o0 = excl, o1 = o0 + c0, o2 = o1 + c1, o3 = o2 + c2;
  if (idx + 3 < hi) {
    *reinterpret_cast<int4*>(offs + idx) = make_int4(o0, o1, o2, o3);
    *reinterpret_cast<int4*>(cur + idx)  = make_int4(o0, o1, o2, o3);
  } else if (idx < hi) {
    offs[idx] = o0; cur[idx] = o0;
    if (idx + 1 < hi) { offs[idx + 1] = o1; cur[idx + 1] = o1; }
    if (idx + 2 < hi) { offs[idx + 2] = o2; cur[idx + 2] = o2; }
  }
}

__global__ void k_fill(const int* __restrict__ vertex, const int* __restrict__ edges,
                       int* __restrict__ curE, int* __restrict__ curV,
                       int* __restrict__ incEv, int* __restrict__ incVe, int nnz) {
  int i = blockIdx.x * blockDim.x + threadIdx.x;
  if (i < nnz) {
    int v = vertex[i], e = edges[i];
    int pe = atomicAdd(&curE[e], 1);
    incEv[pe] = v;
    int pv = atomicAdd(&curV[v], 1);
    incVe[pv] = e;
  }
}

// ---------------- X -> bf16 (into d_out, used as scratch until hop2 rewrites it) ----

__global__ __launch_bounds__(256) void k_xcvt(const float* __restrict__ X,
                                              ushort_t* __restrict__ Xbf, int total4) {
  int i = blockIdx.x * 256 + threadIdx.x;      // one float4 per thread
  if (i < total4) {
    float4 v = reinterpret_cast<const float4*>(X)[i];
    ushort4 r;
    r.x = f2bf(v.x); r.y = f2bf(v.y); r.z = f2bf(v.z); r.w = f2bf(v.w);
    reinterpret_cast<ushort4*>(Xbf)[i] = r;
  }
}

// ---------------- hop 1: mean-aggregate vertices into edges (bf16 rows, f32 accum) ----

__global__ void k_hop1(const ushort_t* __restrict__ Xbf, const float* __restrict__ degE,
                       const int* __restrict__ offsE, const int* __restrict__ incEv,
                       ushort_t* __restrict__ Xe, int M) {
  int gw = (blockIdx.x * blockDim.x + threadIdx.x) >> 6;
  int lane = threadIdx.x & 63;
  if (gw >= M) return;
  int s = offsE[gw], t = offsE[gw + 1];
  float a0 = 0.f, a1 = 0.f, a2 = 0.f, a3 = 0.f;
  const ushort_t* Xl = Xbf + lane * 4;
  for (int k = s; k < t; ++k) {
    int v = incEv[k];
    ushort4 x = *reinterpret_cast<const ushort4*>(Xl + (size_t)v * DD);
    a0 += bf2f(x.x); a1 += bf2f(x.y); a2 += bf2f(x.z); a3 += bf2f(x.w);
  }
  float scale = degE[gw] / fmaxf((float)(t - s), 1.0f);
  ushort4 r;
  r.x = f2bf(a0 * scale); r.y = f2bf(a1 * scale);
  r.z = f2bf(a2 * scale); r.w = f2bf(a3 * scale);
  *reinterpret_cast<ushort4*>(Xe + (size_t)gw * DD + lane * 4) = r;
}

// ---------------- hop 2: sum-aggregate edges into vertices + norm + alpha-mix ----

__global__ void k_hop2(const ushort_t* __restrict__ Xe, const float* __restrict__ X0,
                       const float* __restrict__ degV, const int* __restrict__ offsV,
                       const int* __restrict__ incVe, const float* __restrict__ alpha_p,
                       float* __restrict__ Xi, int N) {
  int gw = (blockIdx.x * blockDim.x + threadIdx.x) >> 6;
  int lane = threadIdx.x & 63;
  if (gw >= N) return;
  int s = offsV[gw], t = offsV[gw + 1];
  float a0 = 0.f, a1 = 0.f, a2 = 0.f, a3 = 0.f;
  const ushort_t* Xel = Xe + lane * 4;
  for (int k = s; k < t; ++k) {
    int e = incVe[k];
    ushort4 x = *reinterpret_cast<const ushort4*>(Xel + (size_t)e * DD);
    a0 += bf2f(x.x); a1 += bf2f(x.y); a2 += bf2f(x.z); a3 += bf2f(x.w);
  }
  float dv = degV[gw];
  a0 *= dv; a1 *= dv; a2 *= dv; a3 *= dv;
  float ss = a0 * a0 + a1 * a1 + a2 * a2 + a3 * a3;
  #pragma unroll
  for (int o = 32; o > 0; o >>= 1) ss += __shfl_down(ss, o);
  ss = __shfl(ss, 0);
  float norm = sqrtf(ss);
  float scl = (norm > 0.f) ? (1.0f / norm) : 0.f;
  float a = alpha_p[0];
  float oma = 1.0f - a;
  float4 x0 = *reinterpret_cast<const float4*>(X0 + (size_t)gw * DD + lane * 4);
  float4 r;
  r.x = oma * (a0 * scl) + a * x0.x;
  r.y = oma * (a1 * scl) + a * x0.y;
  r.z = oma * (a2 * scl) + a * x0.z;
  r.w = oma * (a3 * scl) + a * x0.w;
  *reinterpret_cast<float4*>(Xi + (size_t)gw * DD + lane * 4) = r;
}

// ---------------- W precompute: Wt[col][k] = bf16(W[k][col]) ----------------

__global__ __launch_bounds__(256) void k_wcvt(const float* __restrict__ W,
                                              ushort_t* __restrict__ Wt) {
  int t = blockIdx.x * 256 + threadIdx.x;     // 65536 threads
  int k = t >> 8, c = t & 255;
  Wt[c * 256 + k] = f2bf(W[t]);               // coalesced read of W[k][c]
}

// ---------------- final: out = (1-beta)*Xi + beta*(Xi @ W), bf16 MFMA, in-place ----
// block = 64 rows x 256 cols, 4 waves, each wave 16 rows x 256 cols (16 C-fragments).

__global__ __launch_bounds__(256) void k_gemm_mfma(float* XiOut,
                                                   const ushort_t* __restrict__ Wt,
                                                   const float* __restrict__ beta_p,
                                                   int nrows) {
  __shared__ ushort_t A_lds[64][40];     // 5 KB
  __shared__ ushort_t B_lds[256][40];    // 20 KB
  const int tid = threadIdx.x;
  const int lane = tid & 63;
  const int wid = tid >> 6;
  const int l15 = lane & 15;
  const int l4  = lane >> 4;             // 0..3
  const int row0 = blockIdx.x * 64;

  f32x4 acc[16];
  #pragma unroll
  for (int n = 0; n < 16; ++n) acc[n] = (f32x4){0.f, 0.f, 0.f, 0.f};

  for (int k0 = 0; k0 < 256; k0 += 32) {
    // stage A: 64 rows x 32 k (f32 -> bf16)
    #pragma unroll
    for (int p = 0; p < 2; ++p) {
      int flat = p * 256 + tid;          // 0..511
      int row = flat >> 3;               // 0..63
      int c4  = flat & 7;                // float4 index within the 32-k tile
      int grow = row0 + row;
      float4 av = make_float4(0.f, 0.f, 0.f, 0.f);
      if (grow < nrows)
        av = *reinterpret_cast<const float4*>(XiOut + (size_t)grow * 256 + k0 + c4 * 4);
      uint2 pk;
      pk.x = (uint32_t)f2bf(av.x) | ((uint32_t)f2bf(av.y) << 16);
      pk.y = (uint32_t)f2bf(av.z) | ((uint32_t)f2bf(av.w) << 16);
      *reinterpret_cast<uint2*>(&A_lds[row][c4 * 4]) = pk;
    }
    // stage B: 256 cols x 32 k from Wt[col][k] (already bf16)
    {
      const ushort_t* src = Wt + (size_t)tid * 256 + k0;
      #pragma unroll
      for (int p = 0; p < 4; ++p) {
        int4 wv = *reinterpret_cast<const int4*>(src + p * 8);
        *reinterpret_cast<int4*>(&B_lds[tid][p * 8]) = wv;
      }
    }
    __syncthreads();
    short8v a = *reinterpret_cast<const short8v*>(&A_lds[wid * 16 + l15][l4 * 8]);
    #pragma unroll
    for (int n = 0; n < 16; ++n) {
      short8v bfr = *reinterpret_cast<const short8v*>(&B_lds[n * 16 + l15][l4 * 8]);
      acc[n] = __builtin_amdgcn_mfma_f32_16x16x32_bf16(a, bfr, acc[n], 0, 0, 0);
    }
    __syncthreads();
  }

  // epilogue: out = (1-b)*Xi + b*acc  (C/D layout: col = lane&15, row = (lane>>4)*4 + reg)
  float b = beta_p[0], ob = 1.0f - b;
  int rbase = row0 + wid * 16 + l4 * 4;
  #pragma unroll
  for (int n = 0; n < 16; ++n) {
    int col = n * 16 + l15;
    #pragma unroll
    for (int j = 0; j < 4; ++j) {
      int r = rbase + j;
      if (r < nrows) {
        size_t idx = (size_t)r * 256 + col;
        float xi = XiOut[idx];
        XiOut[idx] = ob * xi + b * acc[n][j];
      }
    }
  }
}

// ---------------- launch ----------------

extern "C" void kernel_launch(void* const* d_in, const int* in_sizes, int n_in,
                              void* d_out, int out_size, void* d_ws, size_t ws_size,
                              hipStream_t stream) {
  const float* X     = (const float*)d_in[0];
  const float* X0    = (const float*)d_in[1];
  const float* W     = (const float*)d_in[2];
  const float* degV  = (const float*)d_in[3];
  const float* degE  = (const float*)d_in[4];
  const int*   vertex= (const int*)d_in[5];
  const int*   edges = (const int*)d_in[6];
  const float* alpha = (const float*)d_in[7];
  const float* beta  = (const float*)d_in[8];

  const int N   = in_sizes[3];   // degV has N elements
  const int M   = in_sizes[4];   // degE has M elements
  const int NNZ = in_sizes[5];

  auto r4 = [](int x) { return (x + 3) & ~3; };
  const int Mr = r4(M), Nr = r4(N);

  int* w = (int*)d_ws;
  int* cntE  = w; w += Mr;
  int* cntV  = w; w += Nr;        // contiguous with cntE for one memset
  int* offsE = w; w += r4(M + 1);
  int* offsV = w; w += r4(N + 1);
  int* curE  = w; w += Mr;
  int* curV  = w; w += Nr;
  int* bsum  = w; w += 128;
  int* bpre  = w; w += 128;
  int* incEv = w; w += r4(NNZ);
  int* incVe = w; w += r4(NNZ);
  uintptr_t p = (uintptr_t)w;
  p = (p + 15) & ~(uintptr_t)15;
  ushort_t* Wt = (ushort_t*)p;           // 256*256 bf16 = 128 KB
  p += (size_t)256 * 256 * sizeof(ushort_t);
  ushort_t* Xe = (ushort_t*)p;           // M*256 bf16 = 10.24 MB
  // total ws: ~4.04 MB ints + 0.13 MB Wt + 10.24 MB Xe = 14.4 MB << proven 24.5 MB

  float*    Xi  = (float*)d_out;         // N*256 f32 (hop2 output, GEMM in-place)
  ushort_t* Xbf = (ushort_t*)d_out;      // N*256 bf16 scratch: dead after hop1,
                                         // fully overwritten by hop2

  hipMemsetAsync(cntE, 0, (size_t)(Mr + Nr) * sizeof(int), stream);

  int nb = (NNZ + 255) / 256;
  k_wcvt <<<256, 256, 0, stream>>>(W, Wt);
  k_xcvt <<<(N * (DD / 4) + 255) / 256, 256, 0, stream>>>(X, Xbf, N * (DD / 4));
  k_count<<<nb, 256, 0, stream>>>(vertex, edges, cntV, cntE, NNZ);
  k_bsum <<<2 * SNB, 256, 0, stream>>>(cntE, cntV, bsum, M, N);
  k_bscan<<<1, 128, 0, stream>>>(bsum, bpre, offsE, offsV, M, N);
  k_woffs<<<2 * SNB, 256, 0, stream>>>(cntE, cntV, bpre, offsE, curE, offsV, curV, M, N);
  k_fill <<<nb, 256, 0, stream>>>(vertex, edges, curE, curV, incEv, incVe, NNZ);

  k_hop1<<<(M + 3) / 4, 256, 0, stream>>>(Xbf, degE, offsE, incEv, Xe, M);
  k_hop2<<<(N + 3) / 4, 256, 0, stream>>>(Xe, X0, degV, offsV, incVe, alpha, Xi, N);
  k_gemm_mfma<<<(N + 63) / 64, 256, 0, stream>>>(Xi, Wt, beta, N);
}

// Round 6
// 245.147 us; speedup vs baseline: 1.8870x; 1.1243x over previous
//
#include <hip/hip_runtime.h>
#include <cstdint>

static constexpr int DD = 256;   // feature dim (fixed by problem)
static constexpr int SNB = 64;   // scan blocks per array

typedef unsigned short ushort_t;
typedef __attribute__((ext_vector_type(8))) short short8v;   // 8 bf16 (4 VGPRs)
typedef __attribute__((ext_vector_type(4))) float f32x4;

static __device__ inline ushort_t f2bf(float f) {     // RNE f32->bf16 (no NaN in data)
  uint32_t u = __builtin_bit_cast(uint32_t, f);
  uint32_t r = (u + 0x7fffu + ((u >> 16) & 1u)) >> 16;
  return (ushort_t)r;
}
static __device__ inline float bf2f(ushort_t u) {
  return __builtin_bit_cast(float, (uint32_t)u << 16);
}

// ---------------- CSR build ----------------

__global__ void k_count(const int* __restrict__ vertex, const int* __restrict__ edges,
                        int* __restrict__ cntV, int* __restrict__ cntE, int nnz) {
  int i = blockIdx.x * blockDim.x + threadIdx.x;
  if (i < nnz) {
    atomicAdd(&cntV[vertex[i]], 1);
    atomicAdd(&cntE[edges[i]], 1);
  }
}

__device__ inline int wave_incl_scan(int v, int lane) {
  #pragma unroll
  for (int o = 1; o < 64; o <<= 1) {
    int u = __shfl_up(v, o);
    if (lane >= o) v += u;
  }
  return v;
}

// Phase 1: per-chunk sums for both arrays. blocks 0..63 -> E, 64..127 -> V.
__global__ __launch_bounds__(256) void k_bsum(const int* __restrict__ cntE,
                                              const int* __restrict__ cntV,
                                              int* __restrict__ bsum, int M, int N) {
  int arr = blockIdx.x >> 6;
  int b = blockIdx.x & 63;
  const int* cnt = arr ? cntV : cntE;
  int n = arr ? N : M;
  int chunk = (((n + SNB - 1) / SNB) + 3) & ~3;
  int lo = b * chunk, hi = min(lo + chunk, n);
  int s = 0;
  for (int i = lo + (int)threadIdx.x; i < hi; i += 256) s += cnt[i];
  #pragma unroll
  for (int o = 32; o; o >>= 1) s += __shfl_down(s, o);
  __shared__ int sh[4];
  if ((threadIdx.x & 63) == 0) sh[threadIdx.x >> 6] = s;
  __syncthreads();
  if (threadIdx.x == 0) bsum[blockIdx.x] = sh[0] + sh[1] + sh[2] + sh[3];
}

// Phase 2: scan the 128 block sums (wave 0 = E, wave 1 = V); write totals.
__global__ __launch_bounds__(128) void k_bscan(const int* __restrict__ bsum,
                                               int* __restrict__ bpre,
                                               int* __restrict__ offsE, int* __restrict__ offsV,
                                               int M, int N) {
  int t = threadIdx.x;
  int lane = t & 63;
  int v = bsum[t];
  int inc = wave_incl_scan(v, lane);
  bpre[t] = inc - v;
  if (lane == 63) {
    if (t < 64) offsE[M] = inc;
    else        offsV[N] = inc;
  }
}

// Phase 3: per-chunk exclusive scan + global base, write offs & cursor (int4).
__global__ __launch_bounds__(256) void k_woffs(const int* __restrict__ cntE,
                                               const int* __restrict__ cntV,
                                               const int* __restrict__ bpre,
                                               int* __restrict__ offsE, int* __restrict__ curE,
                                               int* __restrict__ offsV, int* __restrict__ curV,
                                               int M, int N) {
  int arr = blockIdx.x >> 6;
  int b = blockIdx.x & 63;
  const int* cnt = arr ? cntV : cntE;
  int* offs = arr ? offsV : offsE;
  int* cur  = arr ? curV  : curE;
  int n = arr ? N : M;
  int chunk = (((n + SNB - 1) / SNB) + 3) & ~3;
  int lo = b * chunk, hi = min(lo + chunk, n);
  if (lo >= n) return;
  int base = bpre[blockIdx.x];

  int idx = lo + (int)threadIdx.x * 4;
  int c0 = 0, c1 = 0, c2 = 0, c3 = 0;
  if (idx + 3 < hi) {
    int4 c = *reinterpret_cast<const int4*>(cnt + idx);
    c0 = c.x; c1 = c.y; c2 = c.z; c3 = c.w;
  } else if (idx < hi) {
    c0 = cnt[idx];
    if (idx + 1 < hi) c1 = cnt[idx + 1];
    if (idx + 2 < hi) c2 = cnt[idx + 2];
  }
  int tsum = c0 + c1 + c2 + c3;
  int lane = threadIdx.x & 63, wid = threadIdx.x >> 6;
  int winc = wave_incl_scan(tsum, lane);
  __shared__ int wtot[4];
  if (lane == 63) wtot[wid] = winc;
  __syncthreads();
  int wbase = 0;
  #pragma unroll
  for (int q = 0; q < 4; ++q) wbase += (q < wid) ? wtot[q] : 0;
  int excl = base + wbase + winc - tsum;
  int o0 = excl, o1 = o0 + c0, o2 = o1 + c1, o3 = o2 + c2;
  if (idx + 3 < hi) {
    *reinterpret_cast<int4*>(offs + idx) = make_int4(o0, o1, o2, o3);
    *reinterpret_cast<int4*>(cur + idx)  = make_int4(o0, o1, o2, o3);
  } else if (idx < hi) {
    offs[idx] = o0; cur[idx] = o0;
    if (idx + 1 < hi) { offs[idx + 1] = o1; cur[idx + 1] = o1; }
    if (idx + 2 < hi) { offs[idx + 2] = o2; cur[idx + 2] = o2; }
  }
}

__global__ void k_fill(const int* __restrict__ vertex, const int* __restrict__ edges,
                       int* __restrict__ curE, int* __restrict__ curV,
                       int* __restrict__ incEv, int* __restrict__ incVe, int nnz) {
  int i = blockIdx.x * blockDim.x + threadIdx.x;
  if (i < nnz) {
    int v = vertex[i], e = edges[i];
    int pe = atomicAdd(&curE[e], 1);
    incEv[pe] = v;
    int pv = atomicAdd(&curV[v], 1);
    incVe[pv] = e;
  }
}

// ---------------- X -> bf16 (into d_out, used as scratch until hop2 rewrites it) ----

__global__ __launch_bounds__(256) void k_xcvt(const float* __restrict__ X,
                                              ushort_t* __restrict__ Xbf, int total4) {
  int i = blockIdx.x * 256 + threadIdx.x;      // one float4 per thread
  if (i < total4) {
    float4 v = reinterpret_cast<const float4*>(X)[i];
    ushort4 r;
    r.x = f2bf(v.x); r.y = f2bf(v.y); r.z = f2bf(v.z); r.w = f2bf(v.w);
    reinterpret_cast<ushort4*>(Xbf)[i] = r;
  }
}

// ---------------- hop 1: mean-aggregate vertices into edges ----------------
// bf16 rows, f32 accum; 4x unrolled gather for memory-level parallelism.

__global__ void k_hop1(const ushort_t* __restrict__ Xbf, const float* __restrict__ degE,
                       const int* __restrict__ offsE, const int* __restrict__ incEv,
                       ushort_t* __restrict__ Xe, int M) {
  int gw = (blockIdx.x * blockDim.x + threadIdx.x) >> 6;
  int lane = threadIdx.x & 63;
  if (gw >= M) return;
  int s = offsE[gw], t = offsE[gw + 1];
  float a0 = 0.f, a1 = 0.f, a2 = 0.f, a3 = 0.f;
  const ushort_t* Xl = Xbf + lane * 4;
  int k = s;
  for (; k + 4 <= t; k += 4) {
    int v0 = incEv[k], v1 = incEv[k + 1], v2 = incEv[k + 2], v3 = incEv[k + 3];
    ushort4 x0 = *reinterpret_cast<const ushort4*>(Xl + (size_t)v0 * DD);
    ushort4 x1 = *reinterpret_cast<const ushort4*>(Xl + (size_t)v1 * DD);
    ushort4 x2 = *reinterpret_cast<const ushort4*>(Xl + (size_t)v2 * DD);
    ushort4 x3 = *reinterpret_cast<const ushort4*>(Xl + (size_t)v3 * DD);
    a0 += bf2f(x0.x); a1 += bf2f(x0.y); a2 += bf2f(x0.z); a3 += bf2f(x0.w);
    a0 += bf2f(x1.x); a1 += bf2f(x1.y); a2 += bf2f(x1.z); a3 += bf2f(x1.w);
    a0 += bf2f(x2.x); a1 += bf2f(x2.y); a2 += bf2f(x2.z); a3 += bf2f(x2.w);
    a0 += bf2f(x3.x); a1 += bf2f(x3.y); a2 += bf2f(x3.z); a3 += bf2f(x3.w);
  }
  for (; k < t; ++k) {
    int v = incEv[k];
    ushort4 x = *reinterpret_cast<const ushort4*>(Xl + (size_t)v * DD);
    a0 += bf2f(x.x); a1 += bf2f(x.y); a2 += bf2f(x.z); a3 += bf2f(x.w);
  }
  float scale = degE[gw] / fmaxf((float)(t - s), 1.0f);
  ushort4 r;
  r.x = f2bf(a0 * scale); r.y = f2bf(a1 * scale);
  r.z = f2bf(a2 * scale); r.w = f2bf(a3 * scale);
  *reinterpret_cast<ushort4*>(Xe + (size_t)gw * DD + lane * 4) = r;
}

// ---------------- hop 2: sum-aggregate edges into vertices + norm + alpha-mix ----
// 4x unrolled gather for memory-level parallelism.

__global__ void k_hop2(const ushort_t* __restrict__ Xe, const float* __restrict__ X0,
                       const float* __restrict__ degV, const int* __restrict__ offsV,
                       const int* __restrict__ incVe, const float* __restrict__ alpha_p,
                       float* __restrict__ Xi, int N) {
  int gw = (blockIdx.x * blockDim.x + threadIdx.x) >> 6;
  int lane = threadIdx.x & 63;
  if (gw >= N) return;
  int s = offsV[gw], t = offsV[gw + 1];
  float a0 = 0.f, a1 = 0.f, a2 = 0.f, a3 = 0.f;
  const ushort_t* Xel = Xe + lane * 4;
  int k = s;
  for (; k + 4 <= t; k += 4) {
    int e0 = incVe[k], e1 = incVe[k + 1], e2 = incVe[k + 2], e3 = incVe[k + 3];
    ushort4 x0 = *reinterpret_cast<const ushort4*>(Xel + (size_t)e0 * DD);
    ushort4 x1 = *reinterpret_cast<const ushort4*>(Xel + (size_t)e1 * DD);
    ushort4 x2 = *reinterpret_cast<const ushort4*>(Xel + (size_t)e2 * DD);
    ushort4 x3 = *reinterpret_cast<const ushort4*>(Xel + (size_t)e3 * DD);
    a0 += bf2f(x0.x); a1 += bf2f(x0.y); a2 += bf2f(x0.z); a3 += bf2f(x0.w);
    a0 += bf2f(x1.x); a1 += bf2f(x1.y); a2 += bf2f(x1.z); a3 += bf2f(x1.w);
    a0 += bf2f(x2.x); a1 += bf2f(x2.y); a2 += bf2f(x2.z); a3 += bf2f(x2.w);
    a0 += bf2f(x3.x); a1 += bf2f(x3.y); a2 += bf2f(x3.z); a3 += bf2f(x3.w);
  }
  for (; k < t; ++k) {
    int e = incVe[k];
    ushort4 x = *reinterpret_cast<const ushort4*>(Xel + (size_t)e * DD);
    a0 += bf2f(x.x); a1 += bf2f(x.y); a2 += bf2f(x.z); a3 += bf2f(x.w);
  }
  float dv = degV[gw];
  a0 *= dv; a1 *= dv; a2 *= dv; a3 *= dv;
  float ss = a0 * a0 + a1 * a1 + a2 * a2 + a3 * a3;
  #pragma unroll
  for (int o = 32; o > 0; o >>= 1) ss += __shfl_down(ss, o);
  ss = __shfl(ss, 0);
  float norm = sqrtf(ss);
  float scl = (norm > 0.f) ? (1.0f / norm) : 0.f;
  float a = alpha_p[0];
  float oma = 1.0f - a;
  float4 x0 = *reinterpret_cast<const float4*>(X0 + (size_t)gw * DD + lane * 4);
  float4 r;
  r.x = oma * (a0 * scl) + a * x0.x;
  r.y = oma * (a1 * scl) + a * x0.y;
  r.z = oma * (a2 * scl) + a * x0.z;
  r.w = oma * (a3 * scl) + a * x0.w;
  *reinterpret_cast<float4*>(Xi + (size_t)gw * DD + lane * 4) = r;
}

// ---------------- W precompute: Wt[col][k] = bf16(W[k][col]) ----------------

__global__ __launch_bounds__(256) void k_wcvt(const float* __restrict__ W,
                                              ushort_t* __restrict__ Wt) {
  int t = blockIdx.x * 256 + threadIdx.x;     // 65536 threads
  int k = t >> 8, c = t & 255;
  Wt[c * 256 + k] = f2bf(W[t]);               // coalesced read of W[k][c]
}

// ---------------- final: out = (1-beta)*Xi + beta*(Xi @ W), bf16 MFMA, in-place ----
// block = 64 rows x 256 cols, 4 waves, each wave 16 rows x 256 cols (16 C-fragments).

__global__ __launch_bounds__(256) void k_gemm_mfma(float* XiOut,
                                                   const ushort_t* __restrict__ Wt,
                                                   const float* __restrict__ beta_p,
                                                   int nrows) {
  __shared__ ushort_t A_lds[64][40];     // 5 KB
  __shared__ ushort_t B_lds[256][40];    // 20 KB
  const int tid = threadIdx.x;
  const int lane = tid & 63;
  const int wid = tid >> 6;
  const int l15 = lane & 15;
  const int l4  = lane >> 4;             // 0..3
  const int row0 = blockIdx.x * 64;

  f32x4 acc[16];
  #pragma unroll
  for (int n = 0; n < 16; ++n) acc[n] = (f32x4){0.f, 0.f, 0.f, 0.f};

  for (int k0 = 0; k0 < 256; k0 += 32) {
    // stage A: 64 rows x 32 k (f32 -> bf16)
    #pragma unroll
    for (int p = 0; p < 2; ++p) {
      int flat = p * 256 + tid;          // 0..511
      int row = flat >> 3;               // 0..63
      int c4  = flat & 7;                // float4 index within the 32-k tile
      int grow = row0 + row;
      float4 av = make_float4(0.f, 0.f, 0.f, 0.f);
      if (grow < nrows)
        av = *reinterpret_cast<const float4*>(XiOut + (size_t)grow * 256 + k0 + c4 * 4);
      uint2 pk;
      pk.x = (uint32_t)f2bf(av.x) | ((uint32_t)f2bf(av.y) << 16);
      pk.y = (uint32_t)f2bf(av.z) | ((uint32_t)f2bf(av.w) << 16);
      *reinterpret_cast<uint2*>(&A_lds[row][c4 * 4]) = pk;
    }
    // stage B: 256 cols x 32 k from Wt[col][k] (already bf16)
    {
      const ushort_t* src = Wt + (size_t)tid * 256 + k0;
      #pragma unroll
      for (int p = 0; p < 4; ++p) {
        int4 wv = *reinterpret_cast<const int4*>(src + p * 8);
        *reinterpret_cast<int4*>(&B_lds[tid][p * 8]) = wv;
      }
    }
    __syncthreads();
    short8v a = *reinterpret_cast<const short8v*>(&A_lds[wid * 16 + l15][l4 * 8]);
    #pragma unroll
    for (int n = 0; n < 16; ++n) {
      short8v bfr = *reinterpret_cast<const short8v*>(&B_lds[n * 16 + l15][l4 * 8]);
      acc[n] = __builtin_amdgcn_mfma_f32_16x16x32_bf16(a, bfr, acc[n], 0, 0, 0);
    }
    __syncthreads();
  }

  // epilogue: out = (1-b)*Xi + b*acc  (C/D layout: col = lane&15, row = (lane>>4)*4 + reg)
  float b = beta_p[0], ob = 1.0f - b;
  int rbase = row0 + wid * 16 + l4 * 4;
  #pragma unroll
  for (int n = 0; n < 16; ++n) {
    int col = n * 16 + l15;
    #pragma unroll
    for (int j = 0; j < 4; ++j) {
      int r = rbase + j;
      if (r < nrows) {
        size_t idx = (size_t)r * 256 + col;
        float xi = XiOut[idx];
        XiOut[idx] = ob * xi + b * acc[n][j];
      }
    }
  }
}

// ---------------- launch ----------------

extern "C" void kernel_launch(void* const* d_in, const int* in_sizes, int n_in,
                              void* d_out, int out_size, void* d_ws, size_t ws_size,
                              hipStream_t stream) {
  const float* X     = (const float*)d_in[0];
  const float* X0    = (const float*)d_in[1];
  const float* W     = (const float*)d_in[2];
  const float* degV  = (const float*)d_in[3];
  const float* degE  = (const float*)d_in[4];
  const int*   vertex= (const int*)d_in[5];
  const int*   edges = (const int*)d_in[6];
  const float* alpha = (const float*)d_in[7];
  const float* beta  = (const float*)d_in[8];

  const int N   = in_sizes[3];   // degV has N elements
  const int M   = in_sizes[4];   // degE has M elements
  const int NNZ = in_sizes[5];

  auto r4 = [](int x) { return (x + 3) & ~3; };
  const int Mr = r4(M), Nr = r4(N);

  int* w = (int*)d_ws;
  int* cntE  = w; w += Mr;
  int* cntV  = w; w += Nr;        // contiguous with cntE for one memset
  int* offsE = w; w += r4(M + 1);
  int* offsV = w; w += r4(N + 1);
  int* curE  = w; w += Mr;
  int* curV  = w; w += Nr;
  int* bsum  = w; w += 128;
  int* bpre  = w; w += 128;
  int* incEv = w; w += r4(NNZ);
  int* incVe = w; w += r4(NNZ);
  uintptr_t p = (uintptr_t)w;
  p = (p + 15) & ~(uintptr_t)15;
  ushort_t* Wt = (ushort_t*)p;           // 256*256 bf16 = 128 KB
  p += (size_t)256 * 256 * sizeof(ushort_t);
  ushort_t* Xe = (ushort_t*)p;           // M*256 bf16 = 10.24 MB
  // total ws: ~4.04 MB ints + 0.13 MB Wt + 10.24 MB Xe = 14.4 MB << proven 24.5 MB

  float*    Xi  = (float*)d_out;         // N*256 f32 (hop2 output, GEMM in-place)
  ushort_t* Xbf = (ushort_t*)d_out;      // N*256 bf16 scratch: dead after hop1,
                                         // fully overwritten by hop2

  hipMemsetAsync(cntE, 0, (size_t)(Mr + Nr) * sizeof(int), stream);

  int nb = (NNZ + 255) / 256;
  k_wcvt <<<256, 256, 0, stream>>>(W, Wt);
  k_xcvt <<<(N * (DD / 4) + 255) / 256, 256, 0, stream>>>(X, Xbf, N * (DD / 4));
  k_count<<<nb, 256, 0, stream>>>(vertex, edges, cntV, cntE, NNZ);
  k_bsum <<<2 * SNB, 256, 0, stream>>>(cntE, cntV, bsum, M, N);
  k_bscan<<<1, 128, 0, stream>>>(bsum, bpre, offsE, offsV, M, N);
  k_woffs<<<2 * SNB, 256, 0, stream>>>(cntE, cntV, bpre, offsE, curE, offsV, curV, M, N);
  k_fill <<<nb, 256, 0, stream>>>(vertex, edges, curE, curV, incEv, incVe, NNZ);

  k_hop1<<<(M + 3) / 4, 256, 0, stream>>>(Xbf, degE, offsE, incEv, Xe, M);
  k_hop2<<<(N + 3) / 4, 256, 0, stream>>>(Xe, X0, degV, offsV, incVe, alpha, Xi, N);
  k_gemm_mfma<<<(N + 63) / 64, 256, 0, stream>>>(Xi, Wt, beta, N);
}

// Round 7
// 213.155 us; speedup vs baseline: 2.1702x; 1.1501x over previous
//
#include <hip/hip_runtime.h>
#include <cstdint>

static constexpr int DD = 256;   // feature dim (fixed by problem)
static constexpr int SNB = 64;   // scan blocks per array

typedef unsigned short ushort_t;
typedef __attribute__((ext_vector_type(8))) short short8v;   // 8 bf16 (4 VGPRs)
typedef __attribute__((ext_vector_type(4))) float f32x4;

static __device__ inline ushort_t f2bf(float f) {     // RNE f32->bf16 (no NaN in data)
  uint32_t u = __builtin_bit_cast(uint32_t, f);
  uint32_t r = (u + 0x7fffu + ((u >> 16) & 1u)) >> 16;
  return (ushort_t)r;
}
static __device__ inline float bf2f(ushort_t u) {
  return __builtin_bit_cast(float, (uint32_t)u << 16);
}

// ---------------- CSR build ----------------

__global__ void k_count(const int* __restrict__ vertex, const int* __restrict__ edges,
                        int* __restrict__ cntV, int* __restrict__ cntE, int nnz) {
  int i = blockIdx.x * blockDim.x + threadIdx.x;
  if (i < nnz) {
    atomicAdd(&cntV[vertex[i]], 1);
    atomicAdd(&cntE[edges[i]], 1);
  }
}

__device__ inline int wave_incl_scan(int v, int lane) {
  #pragma unroll
  for (int o = 1; o < 64; o <<= 1) {
    int u = __shfl_up(v, o);
    if (lane >= o) v += u;
  }
  return v;
}

// Phase 1: per-chunk sums for both arrays. blocks 0..63 -> E, 64..127 -> V.
__global__ __launch_bounds__(256) void k_bsum(const int* __restrict__ cntE,
                                              const int* __restrict__ cntV,
                                              int* __restrict__ bsum, int M, int N) {
  int arr = blockIdx.x >> 6;
  int b = blockIdx.x & 63;
  const int* cnt = arr ? cntV : cntE;
  int n = arr ? N : M;
  int chunk = (((n + SNB - 1) / SNB) + 3) & ~3;
  int lo = b * chunk, hi = min(lo + chunk, n);
  int s = 0;
  for (int i = lo + (int)threadIdx.x; i < hi; i += 256) s += cnt[i];
  #pragma unroll
  for (int o = 32; o; o >>= 1) s += __shfl_down(s, o);
  __shared__ int sh[4];
  if ((threadIdx.x & 63) == 0) sh[threadIdx.x >> 6] = s;
  __syncthreads();
  if (threadIdx.x == 0) bsum[blockIdx.x] = sh[0] + sh[1] + sh[2] + sh[3];
}

// Phase 2: scan the 128 block sums (wave 0 = E, wave 1 = V); write totals.
__global__ __launch_bounds__(128) void k_bscan(const int* __restrict__ bsum,
                                               int* __restrict__ bpre,
                                               int* __restrict__ offsE, int* __restrict__ offsV,
                                               int M, int N) {
  int t = threadIdx.x;
  int lane = t & 63;
  int v = bsum[t];
  int inc = wave_incl_scan(v, lane);
  bpre[t] = inc - v;
  if (lane == 63) {
    if (t < 64) offsE[M] = inc;
    else        offsV[N] = inc;
  }
}

// Phase 3: per-chunk exclusive scan + global base, write offs & cursor (int4).
__global__ __launch_bounds__(256) void k_woffs(const int* __restrict__ cntE,
                                               const int* __restrict__ cntV,
                                               const int* __restrict__ bpre,
                                               int* __restrict__ offsE, int* __restrict__ curE,
                                               int* __restrict__ offsV, int* __restrict__ curV,
                                               int M, int N) {
  int arr = blockIdx.x >> 6;
  int b = blockIdx.x & 63;
  const int* cnt = arr ? cntV : cntE;
  int* offs = arr ? offsV : offsE;
  int* cur  = arr ? curV  : curE;
  int n = arr ? N : M;
  int chunk = (((n + SNB - 1) / SNB) + 3) & ~3;
  int lo = b * chunk, hi = min(lo + chunk, n);
  if (lo >= n) return;
  int base = bpre[blockIdx.x];

  int idx = lo + (int)threadIdx.x * 4;
  int c0 = 0, c1 = 0, c2 = 0, c3 = 0;
  if (idx + 3 < hi) {
    int4 c = *reinterpret_cast<const int4*>(cnt + idx);
    c0 = c.x; c1 = c.y; c2 = c.z; c3 = c.w;
  } else if (idx < hi) {
    c0 = cnt[idx];
    if (idx + 1 < hi) c1 = cnt[idx + 1];
    if (idx + 2 < hi) c2 = cnt[idx + 2];
  }
  int tsum = c0 + c1 + c2 + c3;
  int lane = threadIdx.x & 63, wid = threadIdx.x >> 6;
  int winc = wave_incl_scan(tsum, lane);
  __shared__ int wtot[4];
  if (lane == 63) wtot[wid] = winc;
  __syncthreads();
  int wbase = 0;
  #pragma unroll
  for (int q = 0; q < 4; ++q) wbase += (q < wid) ? wtot[q] : 0;
  int excl = base + wbase + winc - tsum;
  int o0 = excl, o1 = o0 + c0, o2 = o1 + c1, o3 = o2 + c2;
  if (idx + 3 < hi) {
    *reinterpret_cast<int4*>(offs + idx) = make_int4(o0, o1, o2, o3);
    *reinterpret_cast<int4*>(cur + idx)  = make_int4(o0, o1, o2, o3);
  } else if (idx < hi) {
    offs[idx] = o0; cur[idx] = o0;
    if (idx + 1 < hi) { offs[idx + 1] = o1; cur[idx + 1] = o1; }
    if (idx + 2 < hi) { offs[idx + 2] = o2; cur[idx + 2] = o2; }
  }
}

__global__ void k_fill(const int* __restrict__ vertex, const int* __restrict__ edges,
                       int* __restrict__ curE, int* __restrict__ curV,
                       int* __restrict__ incEv, int* __restrict__ incVe, int nnz) {
  int i = blockIdx.x * blockDim.x + threadIdx.x;
  if (i < nnz) {
    int v = vertex[i], e = edges[i];
    int pe = atomicAdd(&curE[e], 1);
    incEv[pe] = v;
    int pv = atomicAdd(&curV[v], 1);
    incVe[pv] = e;
  }
}

// ---------------- X -> bf16 (into d_out, used as scratch until hop2 rewrites it) ----

__global__ __launch_bounds__(256) void k_xcvt(const float* __restrict__ X,
                                              ushort_t* __restrict__ Xbf, int total4) {
  int i = blockIdx.x * 256 + threadIdx.x;      // one float4 per thread
  if (i < total4) {
    float4 v = reinterpret_cast<const float4*>(X)[i];
    ushort4 r;
    r.x = f2bf(v.x); r.y = f2bf(v.y); r.z = f2bf(v.z); r.w = f2bf(v.w);
    reinterpret_cast<ushort4*>(Xbf)[i] = r;
  }
}

// ---------------- hop 1: mean-aggregate vertices into edges ----------------
// bf16 rows, f32 accum; 4x unrolled gather for memory-level parallelism.

__global__ void k_hop1(const ushort_t* __restrict__ Xbf, const float* __restrict__ degE,
                       const int* __restrict__ offsE, const int* __restrict__ incEv,
                       ushort_t* __restrict__ Xe, int M) {
  int gw = (blockIdx.x * blockDim.x + threadIdx.x) >> 6;
  int lane = threadIdx.x & 63;
  if (gw >= M) return;
  int s = offsE[gw], t = offsE[gw + 1];
  float a0 = 0.f, a1 = 0.f, a2 = 0.f, a3 = 0.f;
  const ushort_t* Xl = Xbf + lane * 4;
  int k = s;
  for (; k + 4 <= t; k += 4) {
    int v0 = incEv[k], v1 = incEv[k + 1], v2 = incEv[k + 2], v3 = incEv[k + 3];
    ushort4 x0 = *reinterpret_cast<const ushort4*>(Xl + (size_t)v0 * DD);
    ushort4 x1 = *reinterpret_cast<const ushort4*>(Xl + (size_t)v1 * DD);
    ushort4 x2 = *reinterpret_cast<const ushort4*>(Xl + (size_t)v2 * DD);
    ushort4 x3 = *reinterpret_cast<const ushort4*>(Xl + (size_t)v3 * DD);
    a0 += bf2f(x0.x); a1 += bf2f(x0.y); a2 += bf2f(x0.z); a3 += bf2f(x0.w);
    a0 += bf2f(x1.x); a1 += bf2f(x1.y); a2 += bf2f(x1.z); a3 += bf2f(x1.w);
    a0 += bf2f(x2.x); a1 += bf2f(x2.y); a2 += bf2f(x2.z); a3 += bf2f(x2.w);
    a0 += bf2f(x3.x); a1 += bf2f(x3.y); a2 += bf2f(x3.z); a3 += bf2f(x3.w);
  }
  for (; k < t; ++k) {
    int v = incEv[k];
    ushort4 x = *reinterpret_cast<const ushort4*>(Xl + (size_t)v * DD);
    a0 += bf2f(x.x); a1 += bf2f(x.y); a2 += bf2f(x.z); a3 += bf2f(x.w);
  }
  float scale = degE[gw] / fmaxf((float)(t - s), 1.0f);
  ushort4 r;
  r.x = f2bf(a0 * scale); r.y = f2bf(a1 * scale);
  r.z = f2bf(a2 * scale); r.w = f2bf(a3 * scale);
  *reinterpret_cast<ushort4*>(Xe + (size_t)gw * DD + lane * 4) = r;
}

// ---------------- hop 2: sum-aggregate edges into vertices + norm + alpha-mix ----
// 4x unrolled gather for memory-level parallelism.

__global__ void k_hop2(const ushort_t* __restrict__ Xe, const float* __restrict__ X0,
                       const float* __restrict__ degV, const int* __restrict__ offsV,
                       const int* __restrict__ incVe, const float* __restrict__ alpha_p,
                       float* __restrict__ Xi, int N) {
  int gw = (blockIdx.x * blockDim.x + threadIdx.x) >> 6;
  int lane = threadIdx.x & 63;
  if (gw >= N) return;
  int s = offsV[gw], t = offsV[gw + 1];
  float a0 = 0.f, a1 = 0.f, a2 = 0.f, a3 = 0.f;
  const ushort_t* Xel = Xe + lane * 4;
  int k = s;
  for (; k + 4 <= t; k += 4) {
    int e0 = incVe[k], e1 = incVe[k + 1], e2 = incVe[k + 2], e3 = incVe[k + 3];
    ushort4 x0 = *reinterpret_cast<const ushort4*>(Xel + (size_t)e0 * DD);
    ushort4 x1 = *reinterpret_cast<const ushort4*>(Xel + (size_t)e1 * DD);
    ushort4 x2 = *reinterpret_cast<const ushort4*>(Xel + (size_t)e2 * DD);
    ushort4 x3 = *reinterpret_cast<const ushort4*>(Xel + (size_t)e3 * DD);
    a0 += bf2f(x0.x); a1 += bf2f(x0.y); a2 += bf2f(x0.z); a3 += bf2f(x0.w);
    a0 += bf2f(x1.x); a1 += bf2f(x1.y); a2 += bf2f(x1.z); a3 += bf2f(x1.w);
    a0 += bf2f(x2.x); a1 += bf2f(x2.y); a2 += bf2f(x2.z); a3 += bf2f(x2.w);
    a0 += bf2f(x3.x); a1 += bf2f(x3.y); a2 += bf2f(x3.z); a3 += bf2f(x3.w);
  }
  for (; k < t; ++k) {
    int e = incVe[k];
    ushort4 x = *reinterpret_cast<const ushort4*>(Xel + (size_t)e * DD);
    a0 += bf2f(x.x); a1 += bf2f(x.y); a2 += bf2f(x.z); a3 += bf2f(x.w);
  }
  float dv = degV[gw];
  a0 *= dv; a1 *= dv; a2 *= dv; a3 *= dv;
  float ss = a0 * a0 + a1 * a1 + a2 * a2 + a3 * a3;
  #pragma unroll
  for (int o = 32; o > 0; o >>= 1) ss += __shfl_down(ss, o);
  ss = __shfl(ss, 0);
  float norm = sqrtf(ss);
  float scl = (norm > 0.f) ? (1.0f / norm) : 0.f;
  float a = alpha_p[0];
  float oma = 1.0f - a;
  float4 x0 = *reinterpret_cast<const float4*>(X0 + (size_t)gw * DD + lane * 4);
  float4 r;
  r.x = oma * (a0 * scl) + a * x0.x;
  r.y = oma * (a1 * scl) + a * x0.y;
  r.z = oma * (a2 * scl) + a * x0.z;
  r.w = oma * (a3 * scl) + a * x0.w;
  *reinterpret_cast<float4*>(Xi + (size_t)gw * DD + lane * 4) = r;
}

// ---------------- W precompute: Wt[col][k] = bf16(W[k][col]) ----------------

__global__ __launch_bounds__(256) void k_wcvt(const float* __restrict__ W,
                                              ushort_t* __restrict__ Wt) {
  int t = blockIdx.x * 256 + threadIdx.x;     // 65536 threads
  int k = t >> 8, c = t & 255;
  Wt[c * 256 + k] = f2bf(W[t]);               // coalesced read of W[k][c]
}

// ---------------- final: out = (1-beta)*Xi + beta*(Xi @ W), bf16 MFMA, in-place ----
// block = 128 rows x 256 cols (owns its rows exclusively -> in-place safe),
// 512 threads = 8 waves (2 row-waves x 4 col-waves), wave tile 64x64, acc[4][4].
// Per K-step per wave: 4 A + 4 B ds_read_b128 for 16 MFMAs (0.5 reads/MFMA).
// LDS pad = 36 ushorts (18 words): uniform 8 words/bank -> conflict-free b128.

__global__ __launch_bounds__(512, 4) void k_gemm_mfma(float* XiOut,
                                                      const ushort_t* __restrict__ Wt,
                                                      const float* __restrict__ beta_p,
                                                      int nrows) {
  __shared__ ushort_t A_lds[128][36];    // 9.2 KB
  __shared__ ushort_t B_lds[256][36];    // 18.4 KB
  const int tid = threadIdx.x;
  const int lane = tid & 63;
  const int wid = tid >> 6;              // 0..7
  const int wr = wid >> 2;               // 0..1 (row wave)
  const int wc = wid & 3;                // 0..3 (col wave)
  const int l15 = lane & 15;
  const int l4  = lane >> 4;             // 0..3
  const int row0 = blockIdx.x * 128;

  const int t2   = tid & 1;              // which 16-k half of the 32-k tile
  const int arow = tid >> 1;             // 0..255: A row (0..127 used) / B col

  f32x4 acc[4][4];
  #pragma unroll
  for (int m = 0; m < 4; ++m)
    #pragma unroll
    for (int n = 0; n < 4; ++n) acc[m][n] = (f32x4){0.f, 0.f, 0.f, 0.f};

  for (int k0 = 0; k0 < 256; k0 += 32) {
    // ---- stage A: 128 rows x 32 k, f32 -> bf16. thread owns 16 k of one row.
    if (arow < 128) {
      int grow = row0 + arow;
      float4 v0 = make_float4(0.f, 0.f, 0.f, 0.f), v1 = v0, v2 = v0, v3 = v0;
      if (grow < nrows) {
        const float* src = XiOut + (size_t)grow * 256 + k0 + t2 * 16;
        v0 = *reinterpret_cast<const float4*>(src + 0);
        v1 = *reinterpret_cast<const float4*>(src + 4);
        v2 = *reinterpret_cast<const float4*>(src + 8);
        v3 = *reinterpret_cast<const float4*>(src + 12);
      }
      uint4 pk0, pk1;
      pk0.x = (uint32_t)f2bf(v0.x) | ((uint32_t)f2bf(v0.y) << 16);
      pk0.y = (uint32_t)f2bf(v0.z) | ((uint32_t)f2bf(v0.w) << 16);
      pk0.z = (uint32_t)f2bf(v1.x) | ((uint32_t)f2bf(v1.y) << 16);
      pk0.w = (uint32_t)f2bf(v1.z) | ((uint32_t)f2bf(v1.w) << 16);
      pk1.x = (uint32_t)f2bf(v2.x) | ((uint32_t)f2bf(v2.y) << 16);
      pk1.y = (uint32_t)f2bf(v2.z) | ((uint32_t)f2bf(v2.w) << 16);
      pk1.z = (uint32_t)f2bf(v3.x) | ((uint32_t)f2bf(v3.y) << 16);
      pk1.w = (uint32_t)f2bf(v3.z) | ((uint32_t)f2bf(v3.w) << 16);
      *reinterpret_cast<uint4*>(&A_lds[arow][t2 * 16 + 0]) = pk0;
      *reinterpret_cast<uint4*>(&A_lds[arow][t2 * 16 + 8]) = pk1;
    }
    // ---- stage B: 256 cols x 32 k (already bf16). thread owns 16 k of one col.
    {
      const ushort_t* src = Wt + (size_t)arow * 256 + k0 + t2 * 16;
      int4 w0 = *reinterpret_cast<const int4*>(src + 0);
      int4 w1 = *reinterpret_cast<const int4*>(src + 8);
      *reinterpret_cast<int4*>(&B_lds[arow][t2 * 16 + 0]) = w0;
      *reinterpret_cast<int4*>(&B_lds[arow][t2 * 16 + 8]) = w1;
    }
    __syncthreads();
    short8v a[4], b[4];
    #pragma unroll
    for (int m = 0; m < 4; ++m)
      a[m] = *reinterpret_cast<const short8v*>(&A_lds[wr * 64 + m * 16 + l15][l4 * 8]);
    #pragma unroll
    for (int n = 0; n < 4; ++n)
      b[n] = *reinterpret_cast<const short8v*>(&B_lds[wc * 64 + n * 16 + l15][l4 * 8]);
    #pragma unroll
    for (int m = 0; m < 4; ++m)
      #pragma unroll
      for (int n = 0; n < 4; ++n)
        acc[m][n] = __builtin_amdgcn_mfma_f32_16x16x32_bf16(a[m], b[n], acc[m][n], 0, 0, 0);
    __syncthreads();
  }

  // epilogue: out = (1-b)*Xi + b*acc  (C/D: col = lane&15, row = (lane>>4)*4 + j)
  float b = beta_p[0], ob = 1.0f - b;
  int rb0 = row0 + wr * 64;
  int cb0 = wc * 64;
  #pragma unroll
  for (int m = 0; m < 4; ++m) {
    #pragma unroll
    for (int j = 0; j < 4; ++j) {
      int r = rb0 + m * 16 + l4 * 4 + j;
      if (r < nrows) {
        #pragma unroll
        for (int n = 0; n < 4; ++n) {
          size_t idx = (size_t)r * 256 + cb0 + n * 16 + l15;
          float xi = XiOut[idx];
          XiOut[idx] = ob * xi + b * acc[m][n][j];
        }
      }
    }
  }
}

// ---------------- launch ----------------

extern "C" void kernel_launch(void* const* d_in, const int* in_sizes, int n_in,
                              void* d_out, int out_size, void* d_ws, size_t ws_size,
                              hipStream_t stream) {
  const float* X     = (const float*)d_in[0];
  const float* X0    = (const float*)d_in[1];
  const float* W     = (const float*)d_in[2];
  const float* degV  = (const float*)d_in[3];
  const float* degE  = (const float*)d_in[4];
  const int*   vertex= (const int*)d_in[5];
  const int*   edges = (const int*)d_in[6];
  const float* alpha = (const float*)d_in[7];
  const float* beta  = (const float*)d_in[8];

  const int N   = in_sizes[3];   // degV has N elements
  const int M   = in_sizes[4];   // degE has M elements
  const int NNZ = in_sizes[5];

  auto r4 = [](int x) { return (x + 3) & ~3; };
  const int Mr = r4(M), Nr = r4(N);

  int* w = (int*)d_ws;
  int* cntE  = w; w += Mr;
  int* cntV  = w; w += Nr;        // contiguous with cntE for one memset
  int* offsE = w; w += r4(M + 1);
  int* offsV = w; w += r4(N + 1);
  int* curE  = w; w += Mr;
  int* curV  = w; w += Nr;
  int* bsum  = w; w += 128;
  int* bpre  = w; w += 128;
  int* incEv = w; w += r4(NNZ);
  int* incVe = w; w += r4(NNZ);
  uintptr_t p = (uintptr_t)w;
  p = (p + 15) & ~(uintptr_t)15;
  ushort_t* Wt = (ushort_t*)p;           // 256*256 bf16 = 128 KB
  p += (size_t)256 * 256 * sizeof(ushort_t);
  ushort_t* Xe = (ushort_t*)p;           // M*256 bf16 = 10.24 MB
  // total ws: ~4.04 MB ints + 0.13 MB Wt + 10.24 MB Xe = 14.4 MB << proven 24.5 MB

  float*    Xi  = (float*)d_out;         // N*256 f32 (hop2 output, GEMM in-place)
  ushort_t* Xbf = (ushort_t*)d_out;      // N*256 bf16 scratch: dead after hop1,
                                         // fully overwritten by hop2

  hipMemsetAsync(cntE, 0, (size_t)(Mr + Nr) * sizeof(int), stream);

  int nb = (NNZ + 255) / 256;
  k_wcvt <<<256, 256, 0, stream>>>(W, Wt);
  k_xcvt <<<(N * (DD / 4) + 255) / 256, 256, 0, stream>>>(X, Xbf, N * (DD / 4));
  k_count<<<nb, 256, 0, stream>>>(vertex, edges, cntV, cntE, NNZ);
  k_bsum <<<2 * SNB, 256, 0, stream>>>(cntE, cntV, bsum, M, N);
  k_bscan<<<1, 128, 0, stream>>>(bsum, bpre, offsE, offsV, M, N);
  k_woffs<<<2 * SNB, 256, 0, stream>>>(cntE, cntV, bpre, offsE, curE, offsV, curV, M, N);
  k_fill <<<nb, 256, 0, stream>>>(vertex, edges, curE, curV, incEv, incVe, NNZ);

  k_hop1<<<(M + 3) / 4, 256, 0, stream>>>(Xbf, degE, offsE, incEv, Xe, M);
  k_hop2<<<(N + 3) / 4, 256, 0, stream>>>(Xe, X0, degV, offsV, incVe, alpha, Xi, N);
  k_gemm_mfma<<<(N + 127) / 128, 512, 0, stream>>>(Xi, Wt, beta, N);
}

// Round 8
// 210.854 us; speedup vs baseline: 2.1939x; 1.0109x over previous
//
#include <hip/hip_runtime.h>
#include <cstdint>

static constexpr int DD = 256;   // feature dim (fixed by problem)
static constexpr int SNB = 64;   // scan blocks per array

typedef unsigned short ushort_t;
typedef __attribute__((ext_vector_type(8))) short short8v;   // 8 bf16 (4 VGPRs)
typedef __attribute__((ext_vector_type(4))) float f32x4;

static __device__ inline ushort_t f2bf(float f) {     // RNE f32->bf16 (no NaN in data)
  uint32_t u = __builtin_bit_cast(uint32_t, f);
  uint32_t r = (u + 0x7fffu + ((u >> 16) & 1u)) >> 16;
  return (ushort_t)r;
}
static __device__ inline float bf2f(ushort_t u) {
  return __builtin_bit_cast(float, (uint32_t)u << 16);
}
// unpack int4 (8 packed bf16) and accumulate into a[0..7] (static indices only)
static __device__ inline void addbf8(float* a, int4 x) {
  uint32_t ux = (uint32_t)x.x, uy = (uint32_t)x.y;
  uint32_t uz = (uint32_t)x.z, uw = (uint32_t)x.w;
  a[0] += __builtin_bit_cast(float, ux << 16);
  a[1] += __builtin_bit_cast(float, ux & 0xFFFF0000u);
  a[2] += __builtin_bit_cast(float, uy << 16);
  a[3] += __builtin_bit_cast(float, uy & 0xFFFF0000u);
  a[4] += __builtin_bit_cast(float, uz << 16);
  a[5] += __builtin_bit_cast(float, uz & 0xFFFF0000u);
  a[6] += __builtin_bit_cast(float, uw << 16);
  a[7] += __builtin_bit_cast(float, uw & 0xFFFF0000u);
}

// ---------------- CSR build ----------------

__global__ void k_count(const int* __restrict__ vertex, const int* __restrict__ edges,
                        int* __restrict__ cntV, int* __restrict__ cntE, int nnz) {
  int i = blockIdx.x * blockDim.x + threadIdx.x;
  if (i < nnz) {
    atomicAdd(&cntV[vertex[i]], 1);
    atomicAdd(&cntE[edges[i]], 1);
  }
}

__device__ inline int wave_incl_scan(int v, int lane) {
  #pragma unroll
  for (int o = 1; o < 64; o <<= 1) {
    int u = __shfl_up(v, o);
    if (lane >= o) v += u;
  }
  return v;
}

// Phase 1: per-chunk sums for both arrays. blocks 0..63 -> E, 64..127 -> V.
__global__ __launch_bounds__(256) void k_bsum(const int* __restrict__ cntE,
                                              const int* __restrict__ cntV,
                                              int* __restrict__ bsum, int M, int N) {
  int arr = blockIdx.x >> 6;
  int b = blockIdx.x & 63;
  const int* cnt = arr ? cntV : cntE;
  int n = arr ? N : M;
  int chunk = (((n + SNB - 1) / SNB) + 3) & ~3;
  int lo = b * chunk, hi = min(lo + chunk, n);
  int s = 0;
  for (int i = lo + (int)threadIdx.x; i < hi; i += 256) s += cnt[i];
  #pragma unroll
  for (int o = 32; o; o >>= 1) s += __shfl_down(s, o);
  __shared__ int sh[4];
  if ((threadIdx.x & 63) == 0) sh[threadIdx.x >> 6] = s;
  __syncthreads();
  if (threadIdx.x == 0) bsum[blockIdx.x] = sh[0] + sh[1] + sh[2] + sh[3];
}

// Phase 2: scan the 128 block sums (wave 0 = E, wave 1 = V); write totals.
__global__ __launch_bounds__(128) void k_bscan(const int* __restrict__ bsum,
                                               int* __restrict__ bpre,
                                               int* __restrict__ offsE, int* __restrict__ offsV,
                                               int M, int N) {
  int t = threadIdx.x;
  int lane = t & 63;
  int v = bsum[t];
  int inc = wave_incl_scan(v, lane);
  bpre[t] = inc - v;
  if (lane == 63) {
    if (t < 64) offsE[M] = inc;
    else        offsV[N] = inc;
  }
}

// Phase 3: per-chunk exclusive scan + global base, write offs & cursor (int4).
__global__ __launch_bounds__(256) void k_woffs(const int* __restrict__ cntE,
                                               const int* __restrict__ cntV,
                                               const int* __restrict__ bpre,
                                               int* __restrict__ offsE, int* __restrict__ curE,
                                               int* __restrict__ offsV, int* __restrict__ curV,
                                               int M, int N) {
  int arr = blockIdx.x >> 6;
  int b = blockIdx.x & 63;
  const int* cnt = arr ? cntV : cntE;
  int* offs = arr ? offsV : offsE;
  int* cur  = arr ? curV  : curE;
  int n = arr ? N : M;
  int chunk = (((n + SNB - 1) / SNB) + 3) & ~3;
  int lo = b * chunk, hi = min(lo + chunk, n);
  if (lo >= n) return;
  int base = bpre[blockIdx.x];

  int idx = lo + (int)threadIdx.x * 4;
  int c0 = 0, c1 = 0, c2 = 0, c3 = 0;
  if (idx + 3 < hi) {
    int4 c = *reinterpret_cast<const int4*>(cnt + idx);
    c0 = c.x; c1 = c.y; c2 = c.z; c3 = c.w;
  } else if (idx < hi) {
    c0 = cnt[idx];
    if (idx + 1 < hi) c1 = cnt[idx + 1];
    if (idx + 2 < hi) c2 = cnt[idx + 2];
  }
  int tsum = c0 + c1 + c2 + c3;
  int lane = threadIdx.x & 63, wid = threadIdx.x >> 6;
  int winc = wave_incl_scan(tsum, lane);
  __shared__ int wtot[4];
  if (lane == 63) wtot[wid] = winc;
  __syncthreads();
  int wbase = 0;
  #pragma unroll
  for (int q = 0; q < 4; ++q) wbase += (q < wid) ? wtot[q] : 0;
  int excl = base + wbase + winc - tsum;
  int o0 = excl, o1 = o0 + c0, o2 = o1 + c1, o3 = o2 + c2;
  if (idx + 3 < hi) {
    *reinterpret_cast<int4*>(offs + idx) = make_int4(o0, o1, o2, o3);
    *reinterpret_cast<int4*>(cur + idx)  = make_int4(o0, o1, o2, o3);
  } else if (idx < hi) {
    offs[idx] = o0; cur[idx] = o0;
    if (idx + 1 < hi) { offs[idx + 1] = o1; cur[idx + 1] = o1; }
    if (idx + 2 < hi) { offs[idx + 2] = o2; cur[idx + 2] = o2; }
  }
}

__global__ void k_fill(const int* __restrict__ vertex, const int* __restrict__ edges,
                       int* __restrict__ curE, int* __restrict__ curV,
                       int* __restrict__ incEv, int* __restrict__ incVe, int nnz) {
  int i = blockIdx.x * blockDim.x + threadIdx.x;
  if (i < nnz) {
    int v = vertex[i], e = edges[i];
    int pe = atomicAdd(&curE[e], 1);
    incEv[pe] = v;
    int pv = atomicAdd(&curV[v], 1);
    incVe[pv] = e;
  }
}

// ---------------- X -> bf16 (into d_out, used as scratch until hop2 rewrites it) ----

__global__ __launch_bounds__(256) void k_xcvt(const float* __restrict__ X,
                                              ushort_t* __restrict__ Xbf, int total4) {
  int i = blockIdx.x * 256 + threadIdx.x;      // one float4 per thread
  if (i < total4) {
    float4 v = reinterpret_cast<const float4*>(X)[i];
    ushort4 r;
    r.x = f2bf(v.x); r.y = f2bf(v.y); r.z = f2bf(v.z); r.w = f2bf(v.w);
    reinterpret_cast<ushort4*>(Xbf)[i] = r;
  }
}

// ---------------- hop 1: mean-aggregate vertices into edges ----------------
// Pair-gather: wave = 2 halves x 32 lanes; each half loads a DIFFERENT row at
// 16 B/lane (int4 = 8 bf16) -> 1 KB per load instr, 8 rows in flight (4-pair unroll).
// Lane (half,sub) accumulates features sub*8..sub*8+7; halves merged via shfl_xor(32).

__global__ void k_hop1(const ushort_t* __restrict__ Xbf, const float* __restrict__ degE,
                       const int* __restrict__ offsE, const int* __restrict__ incEv,
                       ushort_t* __restrict__ Xe, int M) {
  int gw = (blockIdx.x * blockDim.x + threadIdx.x) >> 6;
  int lane = threadIdx.x & 63;
  if (gw >= M) return;
  int half = lane >> 5, sub = lane & 31;
  int s = offsE[gw], t = offsE[gw + 1];
  float acc[8] = {0.f, 0.f, 0.f, 0.f, 0.f, 0.f, 0.f, 0.f};
  const ushort_t* rowbase = Xbf + sub * 8;
  int k = s;
  for (; k + 8 <= t; k += 8) {
    int4 x[4];
    #pragma unroll
    for (int p = 0; p < 4; ++p) {
      int lo = incEv[k + 2 * p], hi = incEv[k + 2 * p + 1];
      int v = half ? hi : lo;
      x[p] = *reinterpret_cast<const int4*>(rowbase + (size_t)v * DD);
    }
    #pragma unroll
    for (int p = 0; p < 4; ++p) addbf8(acc, x[p]);
  }
  for (; k < t; k += 2) {
    int idx = k + half;
    if (idx < t) {
      int v = incEv[idx];
      int4 x = *reinterpret_cast<const int4*>(rowbase + (size_t)v * DD);
      addbf8(acc, x);
    }
  }
  #pragma unroll
  for (int j = 0; j < 8; ++j) acc[j] += __shfl_xor(acc[j], 32);
  float scale = degE[gw] / fmaxf((float)(t - s), 1.0f);
  // each lane writes its half's 4 features: f0 = sub*8 + half*4
  float b0 = half ? acc[4] : acc[0];
  float b1 = half ? acc[5] : acc[1];
  float b2 = half ? acc[6] : acc[2];
  float b3 = half ? acc[7] : acc[3];
  ushort4 r;
  r.x = f2bf(b0 * scale); r.y = f2bf(b1 * scale);
  r.z = f2bf(b2 * scale); r.w = f2bf(b3 * scale);
  *reinterpret_cast<ushort4*>(Xe + (size_t)gw * DD + sub * 8 + half * 4) = r;
}

// ---------------- hop 2: sum-aggregate edges into vertices + norm + alpha-mix ----
// Same pair-gather structure; full-wave xor-reduce for the row L2 norm.

__global__ void k_hop2(const ushort_t* __restrict__ Xe, const float* __restrict__ X0,
                       const float* __restrict__ degV, const int* __restrict__ offsV,
                       const int* __restrict__ incVe, const float* __restrict__ alpha_p,
                       float* __restrict__ Xi, int N) {
  int gw = (blockIdx.x * blockDim.x + threadIdx.x) >> 6;
  int lane = threadIdx.x & 63;
  if (gw >= N) return;
  int half = lane >> 5, sub = lane & 31;
  int s = offsV[gw], t = offsV[gw + 1];
  float acc[8] = {0.f, 0.f, 0.f, 0.f, 0.f, 0.f, 0.f, 0.f};
  const ushort_t* rowbase = Xe + sub * 8;
  int k = s;
  for (; k + 8 <= t; k += 8) {
    int4 x[4];
    #pragma unroll
    for (int p = 0; p < 4; ++p) {
      int lo = incVe[k + 2 * p], hi = incVe[k + 2 * p + 1];
      int e = half ? hi : lo;
      x[p] = *reinterpret_cast<const int4*>(rowbase + (size_t)e * DD);
    }
    #pragma unroll
    for (int p = 0; p < 4; ++p) addbf8(acc, x[p]);
  }
  for (; k < t; k += 2) {
    int idx = k + half;
    if (idx < t) {
      int e = incVe[idx];
      int4 x = *reinterpret_cast<const int4*>(rowbase + (size_t)e * DD);
      addbf8(acc, x);
    }
  }
  #pragma unroll
  for (int j = 0; j < 8; ++j) acc[j] += __shfl_xor(acc[j], 32);
  float dv = degV[gw];
  // my 4 features: f0 = sub*8 + half*4
  float b0 = (half ? acc[4] : acc[0]) * dv;
  float b1 = (half ? acc[5] : acc[1]) * dv;
  float b2 = (half ? acc[6] : acc[2]) * dv;
  float b3 = (half ? acc[7] : acc[3]) * dv;
  float ss = b0 * b0 + b1 * b1 + b2 * b2 + b3 * b3;
  #pragma unroll
  for (int o = 1; o < 64; o <<= 1) ss += __shfl_xor(ss, o);
  float norm = sqrtf(ss);
  float scl = (norm > 0.f) ? (1.0f / norm) : 0.f;
  float a = alpha_p[0];
  float oma = 1.0f - a;
  int f0 = sub * 8 + half * 4;
  float4 x0 = *reinterpret_cast<const float4*>(X0 + (size_t)gw * DD + f0);
  float4 r;
  r.x = oma * (b0 * scl) + a * x0.x;
  r.y = oma * (b1 * scl) + a * x0.y;
  r.z = oma * (b2 * scl) + a * x0.z;
  r.w = oma * (b3 * scl) + a * x0.w;
  *reinterpret_cast<float4*>(Xi + (size_t)gw * DD + f0) = r;
}

// ---------------- W precompute: Wt[col][k] = bf16(W[k][col]) ----------------

__global__ __launch_bounds__(256) void k_wcvt(const float* __restrict__ W,
                                              ushort_t* __restrict__ Wt) {
  int t = blockIdx.x * 256 + threadIdx.x;     // 65536 threads
  int k = t >> 8, c = t & 255;
  Wt[c * 256 + k] = f2bf(W[t]);               // coalesced read of W[k][c]
}

// ---------------- final: out = (1-beta)*Xi + beta*(Xi @ W), bf16 MFMA, in-place ----
// block = 128 rows x 256 cols (owns its rows exclusively -> in-place safe),
// 512 threads = 8 waves (2 row-waves x 4 col-waves), wave tile 64x64, acc[4][4].

__global__ __launch_bounds__(512, 4) void k_gemm_mfma(float* XiOut,
                                                      const ushort_t* __restrict__ Wt,
                                                      const float* __restrict__ beta_p,
                                                      int nrows) {
  __shared__ ushort_t A_lds[128][36];    // 9.2 KB
  __shared__ ushort_t B_lds[256][36];    // 18.4 KB
  const int tid = threadIdx.x;
  const int lane = tid & 63;
  const int wid = tid >> 6;              // 0..7
  const int wr = wid >> 2;               // 0..1 (row wave)
  const int wc = wid & 3;                // 0..3 (col wave)
  const int l15 = lane & 15;
  const int l4  = lane >> 4;             // 0..3
  const int row0 = blockIdx.x * 128;

  const int t2   = tid & 1;              // which 16-k half of the 32-k tile
  const int arow = tid >> 1;             // 0..255: A row (0..127 used) / B col

  f32x4 acc[4][4];
  #pragma unroll
  for (int m = 0; m < 4; ++m)
    #pragma unroll
    for (int n = 0; n < 4; ++n) acc[m][n] = (f32x4){0.f, 0.f, 0.f, 0.f};

  for (int k0 = 0; k0 < 256; k0 += 32) {
    // ---- stage A: 128 rows x 32 k, f32 -> bf16. thread owns 16 k of one row.
    if (arow < 128) {
      int grow = row0 + arow;
      float4 v0 = make_float4(0.f, 0.f, 0.f, 0.f), v1 = v0, v2 = v0, v3 = v0;
      if (grow < nrows) {
        const float* src = XiOut + (size_t)grow * 256 + k0 + t2 * 16;
        v0 = *reinterpret_cast<const float4*>(src + 0);
        v1 = *reinterpret_cast<const float4*>(src + 4);
        v2 = *reinterpret_cast<const float4*>(src + 8);
        v3 = *reinterpret_cast<const float4*>(src + 12);
      }
      uint4 pk0, pk1;
      pk0.x = (uint32_t)f2bf(v0.x) | ((uint32_t)f2bf(v0.y) << 16);
      pk0.y = (uint32_t)f2bf(v0.z) | ((uint32_t)f2bf(v0.w) << 16);
      pk0.z = (uint32_t)f2bf(v1.x) | ((uint32_t)f2bf(v1.y) << 16);
      pk0.w = (uint32_t)f2bf(v1.z) | ((uint32_t)f2bf(v1.w) << 16);
      pk1.x = (uint32_t)f2bf(v2.x) | ((uint32_t)f2bf(v2.y) << 16);
      pk1.y = (uint32_t)f2bf(v2.z) | ((uint32_t)f2bf(v2.w) << 16);
      pk1.z = (uint32_t)f2bf(v3.x) | ((uint32_t)f2bf(v3.y) << 16);
      pk1.w = (uint32_t)f2bf(v3.z) | ((uint32_t)f2bf(v3.w) << 16);
      *reinterpret_cast<uint4*>(&A_lds[arow][t2 * 16 + 0]) = pk0;
      *reinterpret_cast<uint4*>(&A_lds[arow][t2 * 16 + 8]) = pk1;
    }
    // ---- stage B: 256 cols x 32 k (already bf16). thread owns 16 k of one col.
    {
      const ushort_t* src = Wt + (size_t)arow * 256 + k0 + t2 * 16;
      int4 w0 = *reinterpret_cast<const int4*>(src + 0);
      int4 w1 = *reinterpret_cast<const int4*>(src + 8);
      *reinterpret_cast<int4*>(&B_lds[arow][t2 * 16 + 0]) = w0;
      *reinterpret_cast<int4*>(&B_lds[arow][t2 * 16 + 8]) = w1;
    }
    __syncthreads();
    short8v a[4], b[4];
    #pragma unroll
    for (int m = 0; m < 4; ++m)
      a[m] = *reinterpret_cast<const short8v*>(&A_lds[wr * 64 + m * 16 + l15][l4 * 8]);
    #pragma unroll
    for (int n = 0; n < 4; ++n)
      b[n] = *reinterpret_cast<const short8v*>(&B_lds[wc * 64 + n * 16 + l15][l4 * 8]);
    #pragma unroll
    for (int m = 0; m < 4; ++m)
      #pragma unroll
      for (int n = 0; n < 4; ++n)
        acc[m][n] = __builtin_amdgcn_mfma_f32_16x16x32_bf16(a[m], b[n], acc[m][n], 0, 0, 0);
    __syncthreads();
  }

  // epilogue: out = (1-b)*Xi + b*acc  (C/D: col = lane&15, row = (lane>>4)*4 + j)
  float b = beta_p[0], ob = 1.0f - b;
  int rb0 = row0 + wr * 64;
  int cb0 = wc * 64;
  #pragma unroll
  for (int m = 0; m < 4; ++m) {
    #pragma unroll
    for (int j = 0; j < 4; ++j) {
      int r = rb0 + m * 16 + l4 * 4 + j;
      if (r < nrows) {
        #pragma unroll
        for (int n = 0; n < 4; ++n) {
          size_t idx = (size_t)r * 256 + cb0 + n * 16 + l15;
          float xi = XiOut[idx];
          XiOut[idx] = ob * xi + b * acc[m][n][j];
        }
      }
    }
  }
}

// ---------------- launch ----------------

extern "C" void kernel_launch(void* const* d_in, const int* in_sizes, int n_in,
                              void* d_out, int out_size, void* d_ws, size_t ws_size,
                              hipStream_t stream) {
  const float* X     = (const float*)d_in[0];
  const float* X0    = (const float*)d_in[1];
  const float* W     = (const float*)d_in[2];
  const float* degV  = (const float*)d_in[3];
  const float* degE  = (const float*)d_in[4];
  const int*   vertex= (const int*)d_in[5];
  const int*   edges = (const int*)d_in[6];
  const float* alpha = (const float*)d_in[7];
  const float* beta  = (const float*)d_in[8];

  const int N   = in_sizes[3];   // degV has N elements
  const int M   = in_sizes[4];   // degE has M elements
  const int NNZ = in_sizes[5];

  auto r4 = [](int x) { return (x + 3) & ~3; };
  const int Mr = r4(M), Nr = r4(N);

  int* w = (int*)d_ws;
  int* cntE  = w; w += Mr;
  int* cntV  = w; w += Nr;        // contiguous with cntE for one memset
  int* offsE = w; w += r4(M + 1);
  int* offsV = w; w += r4(N + 1);
  int* curE  = w; w += Mr;
  int* curV  = w; w += Nr;
  int* bsum  = w; w += 128;
  int* bpre  = w; w += 128;
  int* incEv = w; w += r4(NNZ);
  int* incVe = w; w += r4(NNZ);
  uintptr_t p = (uintptr_t)w;
  p = (p + 15) & ~(uintptr_t)15;
  ushort_t* Wt = (ushort_t*)p;           // 256*256 bf16 = 128 KB
  p += (size_t)256 * 256 * sizeof(ushort_t);
  ushort_t* Xe = (ushort_t*)p;           // M*256 bf16 = 10.24 MB
  // total ws: ~4.04 MB ints + 0.13 MB Wt + 10.24 MB Xe = 14.4 MB << proven 24.5 MB

  float*    Xi  = (float*)d_out;         // N*256 f32 (hop2 output, GEMM in-place)
  ushort_t* Xbf = (ushort_t*)d_out;      // N*256 bf16 scratch: dead after hop1,
                                         // fully overwritten by hop2

  hipMemsetAsync(cntE, 0, (size_t)(Mr + Nr) * sizeof(int), stream);

  int nb = (NNZ + 255) / 256;
  k_wcvt <<<256, 256, 0, stream>>>(W, Wt);
  k_xcvt <<<(N * (DD / 4) + 255) / 256, 256, 0, stream>>>(X, Xbf, N * (DD / 4));
  k_count<<<nb, 256, 0, stream>>>(vertex, edges, cntV, cntE, NNZ);
  k_bsum <<<2 * SNB, 256, 0, stream>>>(cntE, cntV, bsum, M, N);
  k_bscan<<<1, 128, 0, stream>>>(bsum, bpre, offsE, offsV, M, N);
  k_woffs<<<2 * SNB, 256, 0, stream>>>(cntE, cntV, bpre, offsE, curE, offsV, curV, M, N);
  k_fill <<<nb, 256, 0, stream>>>(vertex, edges, curE, curV, incEv, incVe, NNZ);

  k_hop1<<<(M + 3) / 4, 256, 0, stream>>>(Xbf, degE, offsE, incEv, Xe, M);
  k_hop2<<<(N + 3) / 4, 256, 0, stream>>>(Xe, X0, degV, offsV, incVe, alpha, Xi, N);
  k_gemm_mfma<<<(N + 127) / 128, 512, 0, stream>>>(Xi, Wt, beta, N);
}

// Round 9
// 206.605 us; speedup vs baseline: 2.2390x; 1.0206x over previous
//
#include <hip/hip_runtime.h>
#include <cstdint>

static constexpr int DD = 256;   // feature dim (fixed by problem)
static constexpr int SNB = 64;   // scan blocks per array

typedef unsigned short ushort_t;
typedef __attribute__((ext_vector_type(8))) short short8v;   // 8 bf16 (4 VGPRs)
typedef __attribute__((ext_vector_type(4))) float f32x4;

static __device__ inline ushort_t f2bf(float f) {     // RNE f32->bf16 (no NaN in data)
  uint32_t u = __builtin_bit_cast(uint32_t, f);
  uint32_t r = (u + 0x7fffu + ((u >> 16) & 1u)) >> 16;
  return (ushort_t)r;
}
static __device__ inline float bf2f(ushort_t u) {
  return __builtin_bit_cast(float, (uint32_t)u << 16);
}
// unpack int4 (8 packed bf16) and accumulate into a[0..7] (static indices only)
static __device__ inline void addbf8(float* a, int4 x) {
  uint32_t ux = (uint32_t)x.x, uy = (uint32_t)x.y;
  uint32_t uz = (uint32_t)x.z, uw = (uint32_t)x.w;
  a[0] += __builtin_bit_cast(float, ux << 16);
  a[1] += __builtin_bit_cast(float, ux & 0xFFFF0000u);
  a[2] += __builtin_bit_cast(float, uy << 16);
  a[3] += __builtin_bit_cast(float, uy & 0xFFFF0000u);
  a[4] += __builtin_bit_cast(float, uz << 16);
  a[5] += __builtin_bit_cast(float, uz & 0xFFFF0000u);
  a[6] += __builtin_bit_cast(float, uw << 16);
  a[7] += __builtin_bit_cast(float, uw & 0xFFFF0000u);
}

// ---------------- CSR build ----------------

__global__ void k_count(const int* __restrict__ vertex, const int* __restrict__ edges,
                        int* __restrict__ cntV, int* __restrict__ cntE, int nnz) {
  int i = blockIdx.x * blockDim.x + threadIdx.x;
  if (i < nnz) {
    atomicAdd(&cntV[vertex[i]], 1);
    atomicAdd(&cntE[edges[i]], 1);
  }
}

__device__ inline int wave_incl_scan(int v, int lane) {
  #pragma unroll
  for (int o = 1; o < 64; o <<= 1) {
    int u = __shfl_up(v, o);
    if (lane >= o) v += u;
  }
  return v;
}

// Phase 1: per-chunk sums for both arrays. blocks 0..63 -> E, 64..127 -> V.
__global__ __launch_bounds__(256) void k_bsum(const int* __restrict__ cntE,
                                              const int* __restrict__ cntV,
                                              int* __restrict__ bsum, int M, int N) {
  int arr = blockIdx.x >> 6;
  int b = blockIdx.x & 63;
  const int* cnt = arr ? cntV : cntE;
  int n = arr ? N : M;
  int chunk = (((n + SNB - 1) / SNB) + 3) & ~3;
  int lo = b * chunk, hi = min(lo + chunk, n);
  int s = 0;
  for (int i = lo + (int)threadIdx.x; i < hi; i += 256) s += cnt[i];
  #pragma unroll
  for (int o = 32; o; o >>= 1) s += __shfl_down(s, o);
  __shared__ int sh[4];
  if ((threadIdx.x & 63) == 0) sh[threadIdx.x >> 6] = s;
  __syncthreads();
  if (threadIdx.x == 0) bsum[blockIdx.x] = sh[0] + sh[1] + sh[2] + sh[3];
}

// Phase 2: scan the 128 block sums (wave 0 = E, wave 1 = V); write totals.
__global__ __launch_bounds__(128) void k_bscan(const int* __restrict__ bsum,
                                               int* __restrict__ bpre,
                                               int* __restrict__ offsE, int* __restrict__ offsV,
                                               int M, int N) {
  int t = threadIdx.x;
  int lane = t & 63;
  int v = bsum[t];
  int inc = wave_incl_scan(v, lane);
  bpre[t] = inc - v;
  if (lane == 63) {
    if (t < 64) offsE[M] = inc;
    else        offsV[N] = inc;
  }
}

// Phase 3: per-chunk exclusive scan + global base, write offs & cursor (int4).
__global__ __launch_bounds__(256) void k_woffs(const int* __restrict__ cntE,
                                               const int* __restrict__ cntV,
                                               const int* __restrict__ bpre,
                                               int* __restrict__ offsE, int* __restrict__ curE,
                                               int* __restrict__ offsV, int* __restrict__ curV,
                                               int M, int N) {
  int arr = blockIdx.x >> 6;
  int b = blockIdx.x & 63;
  const int* cnt = arr ? cntV : cntE;
  int* offs = arr ? offsV : offsE;
  int* cur  = arr ? curV  : curE;
  int n = arr ? N : M;
  int chunk = (((n + SNB - 1) / SNB) + 3) & ~3;
  int lo = b * chunk, hi = min(lo + chunk, n);
  if (lo >= n) return;
  int base = bpre[blockIdx.x];

  int idx = lo + (int)threadIdx.x * 4;
  int c0 = 0, c1 = 0, c2 = 0, c3 = 0;
  if (idx + 3 < hi) {
    int4 c = *reinterpret_cast<const int4*>(cnt + idx);
    c0 = c.x; c1 = c.y; c2 = c.z; c3 = c.w;
  } else if (idx < hi) {
    c0 = cnt[idx];
    if (idx + 1 < hi) c1 = cnt[idx + 1];
    if (idx + 2 < hi) c2 = cnt[idx + 2];
  }
  int tsum = c0 + c1 + c2 + c3;
  int lane = threadIdx.x & 63, wid = threadIdx.x >> 6;
  int winc = wave_incl_scan(tsum, lane);
  __shared__ int wtot[4];
  if (lane == 63) wtot[wid] = winc;
  __syncthreads();
  int wbase = 0;
  #pragma unroll
  for (int q = 0; q < 4; ++q) wbase += (q < wid) ? wtot[q] : 0;
  int excl = base + wbase + winc - tsum;
  int o0 = excl, o1 = o0 + c0, o2 = o1 + c1, o3 = o2 + c2;
  if (idx + 3 < hi) {
    *reinterpret_cast<int4*>(offs + idx) = make_int4(o0, o1, o2, o3);
    *reinterpret_cast<int4*>(cur + idx)  = make_int4(o0, o1, o2, o3);
  } else if (idx < hi) {
    offs[idx] = o0; cur[idx] = o0;
    if (idx + 1 < hi) { offs[idx + 1] = o1; cur[idx + 1] = o1; }
    if (idx + 2 < hi) { offs[idx + 2] = o2; cur[idx + 2] = o2; }
  }
}

// ushort incidence lists: N=50000, M=20000 both < 65536 -> 2B ids halve the
// scatter payload and the dirty-line writeback count.
__global__ void k_fill(const int* __restrict__ vertex, const int* __restrict__ edges,
                       int* __restrict__ curE, int* __restrict__ curV,
                       ushort_t* __restrict__ incEv, ushort_t* __restrict__ incVe, int nnz) {
  int i = blockIdx.x * blockDim.x + threadIdx.x;
  if (i < nnz) {
    int v = vertex[i], e = edges[i];
    int pe = atomicAdd(&curE[e], 1);
    incEv[pe] = (ushort_t)v;
    int pv = atomicAdd(&curV[v], 1);
    incVe[pv] = (ushort_t)e;
  }
}

// ---------------- X -> bf16 (into d_out, used as scratch until hop2 rewrites it) ----

__global__ __launch_bounds__(256) void k_xcvt(const float* __restrict__ X,
                                              ushort_t* __restrict__ Xbf, int total4) {
  int i = blockIdx.x * 256 + threadIdx.x;      // one float4 per thread
  if (i < total4) {
    float4 v = reinterpret_cast<const float4*>(X)[i];
    ushort4 r;
    r.x = f2bf(v.x); r.y = f2bf(v.y); r.z = f2bf(v.z); r.w = f2bf(v.w);
    reinterpret_cast<ushort4*>(Xbf)[i] = r;
  }
}

// ---------------- hop 1: mean-aggregate vertices into edges ----------------
// Pair-gather + branch-free masked unroll: every wave runs ceil(deg/8) iters of
// 4 independent 1KB loads; dead slots hit the zero row (exact +0.0, L2-resident).

__global__ void k_hop1(const ushort_t* __restrict__ Xbf, const float* __restrict__ degE,
                       const int* __restrict__ offsE, const ushort_t* __restrict__ incEv,
                       ushort_t* __restrict__ Xe, int M, int zrow) {
  int gw = (blockIdx.x * blockDim.x + threadIdx.x) >> 6;
  int lane = threadIdx.x & 63;
  if (gw >= M) return;
  int half = lane >> 5, sub = lane & 31;
  int s = offsE[gw], t = offsE[gw + 1];
  float acc[8] = {0.f, 0.f, 0.f, 0.f, 0.f, 0.f, 0.f, 0.f};
  const ushort_t* rowbase = Xbf + sub * 8;
  for (int k = s; k < t; k += 8) {
    int4 x[4];
    #pragma unroll
    for (int p = 0; p < 4; ++p) {
      int i0 = k + 2 * p + half;
      int j = min(i0, t - 1);
      int idx = (i0 < t) ? (int)incEv[j] : zrow;
      x[p] = *reinterpret_cast<const int4*>(rowbase + (size_t)idx * DD);
    }
    #pragma unroll
    for (int p = 0; p < 4; ++p) addbf8(acc, x[p]);
  }
  #pragma unroll
  for (int j = 0; j < 8; ++j) acc[j] += __shfl_xor(acc[j], 32);
  float scale = degE[gw] / fmaxf((float)(t - s), 1.0f);
  float b0 = half ? acc[4] : acc[0];
  float b1 = half ? acc[5] : acc[1];
  float b2 = half ? acc[6] : acc[2];
  float b3 = half ? acc[7] : acc[3];
  ushort4 r;
  r.x = f2bf(b0 * scale); r.y = f2bf(b1 * scale);
  r.z = f2bf(b2 * scale); r.w = f2bf(b3 * scale);
  *reinterpret_cast<ushort4*>(Xe + (size_t)gw * DD + sub * 8 + half * 4) = r;
}

// ---------------- hop 2: sum-aggregate edges into vertices + norm + alpha-mix ----

__global__ void k_hop2(const ushort_t* __restrict__ Xe, const float* __restrict__ X0,
                       const float* __restrict__ degV, const int* __restrict__ offsV,
                       const ushort_t* __restrict__ incVe, const float* __restrict__ alpha_p,
                       float* __restrict__ Xi, int N, int zrow) {
  int gw = (blockIdx.x * blockDim.x + threadIdx.x) >> 6;
  int lane = threadIdx.x & 63;
  if (gw >= N) return;
  int half = lane >> 5, sub = lane & 31;
  int s = offsV[gw], t = offsV[gw + 1];
  float acc[8] = {0.f, 0.f, 0.f, 0.f, 0.f, 0.f, 0.f, 0.f};
  const ushort_t* rowbase = Xe + sub * 8;
  for (int k = s; k < t; k += 8) {
    int4 x[4];
    #pragma unroll
    for (int p = 0; p < 4; ++p) {
      int i0 = k + 2 * p + half;
      int j = min(i0, t - 1);
      int idx = (i0 < t) ? (int)incVe[j] : zrow;
      x[p] = *reinterpret_cast<const int4*>(rowbase + (size_t)idx * DD);
    }
    #pragma unroll
    for (int p = 0; p < 4; ++p) addbf8(acc, x[p]);
  }
  #pragma unroll
  for (int j = 0; j < 8; ++j) acc[j] += __shfl_xor(acc[j], 32);
  float dv = degV[gw];
  float b0 = (half ? acc[4] : acc[0]) * dv;
  float b1 = (half ? acc[5] : acc[1]) * dv;
  float b2 = (half ? acc[6] : acc[2]) * dv;
  float b3 = (half ? acc[7] : acc[3]) * dv;
  float ss = b0 * b0 + b1 * b1 + b2 * b2 + b3 * b3;
  #pragma unroll
  for (int o = 1; o < 64; o <<= 1) ss += __shfl_xor(ss, o);
  float norm = sqrtf(ss);
  float scl = (norm > 0.f) ? (1.0f / norm) : 0.f;
  float a = alpha_p[0];
  float oma = 1.0f - a;
  int f0 = sub * 8 + half * 4;
  float4 x0 = *reinterpret_cast<const float4*>(X0 + (size_t)gw * DD + f0);
  float4 r;
  r.x = oma * (b0 * scl) + a * x0.x;
  r.y = oma * (b1 * scl) + a * x0.y;
  r.z = oma * (b2 * scl) + a * x0.z;
  r.w = oma * (b3 * scl) + a * x0.w;
  *reinterpret_cast<float4*>(Xi + (size_t)gw * DD + f0) = r;
}

// ---------------- W precompute + zero-row init ----------------
// Wt[col][k] = bf16(W[k][col]); block 0 also zeroes Xe row M and Xbf row N
// (the masked-gather targets).

__global__ __launch_bounds__(256) void k_wcvt(const float* __restrict__ W,
                                              ushort_t* __restrict__ Wt,
                                              ushort_t* __restrict__ XeZ,
                                              ushort_t* __restrict__ XbfZ) {
  int t = blockIdx.x * 256 + threadIdx.x;     // 65536 threads
  int k = t >> 8, c = t & 255;
  Wt[c * 256 + k] = f2bf(W[t]);               // coalesced read of W[k][c]
  if (blockIdx.x == 0) {
    int4 z = make_int4(0, 0, 0, 0);
    if (threadIdx.x < 32)       reinterpret_cast<int4*>(XeZ)[threadIdx.x] = z;
    else if (threadIdx.x < 64)  reinterpret_cast<int4*>(XbfZ)[threadIdx.x - 32] = z;
  }
}

// ---------------- final: out = (1-beta)*Xi + beta*(Xi @ W), bf16 MFMA, in-place ----
// block = 128 rows x 256 cols (owns its rows exclusively -> in-place safe),
// 512 threads = 8 waves (2 row-waves x 4 col-waves), wave tile 64x64, acc[4][4].

__global__ __launch_bounds__(512, 4) void k_gemm_mfma(float* XiOut,
                                                      const ushort_t* __restrict__ Wt,
                                                      const float* __restrict__ beta_p,
                                                      int nrows) {
  __shared__ ushort_t A_lds[128][36];    // 9.2 KB
  __shared__ ushort_t B_lds[256][36];    // 18.4 KB
  const int tid = threadIdx.x;
  const int lane = tid & 63;
  const int wid = tid >> 6;              // 0..7
  const int wr = wid >> 2;               // 0..1 (row wave)
  const int wc = wid & 3;                // 0..3 (col wave)
  const int l15 = lane & 15;
  const int l4  = lane >> 4;             // 0..3
  const int row0 = blockIdx.x * 128;

  const int t2   = tid & 1;              // which 16-k half of the 32-k tile
  const int arow = tid >> 1;             // 0..255: A row (0..127 used) / B col

  f32x4 acc[4][4];
  #pragma unroll
  for (int m = 0; m < 4; ++m)
    #pragma unroll
    for (int n = 0; n < 4; ++n) acc[m][n] = (f32x4){0.f, 0.f, 0.f, 0.f};

  for (int k0 = 0; k0 < 256; k0 += 32) {
    // ---- stage A: 128 rows x 32 k, f32 -> bf16. thread owns 16 k of one row.
    if (arow < 128) {
      int grow = row0 + arow;
      float4 v0 = make_float4(0.f, 0.f, 0.f, 0.f), v1 = v0, v2 = v0, v3 = v0;
      if (grow < nrows) {
        const float* src = XiOut + (size_t)grow * 256 + k0 + t2 * 16;
        v0 = *reinterpret_cast<const float4*>(src + 0);
        v1 = *reinterpret_cast<const float4*>(src + 4);
        v2 = *reinterpret_cast<const float4*>(src + 8);
        v3 = *reinterpret_cast<const float4*>(src + 12);
      }
      uint4 pk0, pk1;
      pk0.x = (uint32_t)f2bf(v0.x) | ((uint32_t)f2bf(v0.y) << 16);
      pk0.y = (uint32_t)f2bf(v0.z) | ((uint32_t)f2bf(v0.w) << 16);
      pk0.z = (uint32_t)f2bf(v1.x) | ((uint32_t)f2bf(v1.y) << 16);
      pk0.w = (uint32_t)f2bf(v1.z) | ((uint32_t)f2bf(v1.w) << 16);
      pk1.x = (uint32_t)f2bf(v2.x) | ((uint32_t)f2bf(v2.y) << 16);
      pk1.y = (uint32_t)f2bf(v2.z) | ((uint32_t)f2bf(v2.w) << 16);
      pk1.z = (uint32_t)f2bf(v3.x) | ((uint32_t)f2bf(v3.y) << 16);
      pk1.w = (uint32_t)f2bf(v3.z) | ((uint32_t)f2bf(v3.w) << 16);
      *reinterpret_cast<uint4*>(&A_lds[arow][t2 * 16 + 0]) = pk0;
      *reinterpret_cast<uint4*>(&A_lds[arow][t2 * 16 + 8]) = pk1;
    }
    // ---- stage B: 256 cols x 32 k (already bf16). thread owns 16 k of one col.
    {
      const ushort_t* src = Wt + (size_t)arow * 256 + k0 + t2 * 16;
      int4 w0 = *reinterpret_cast<const int4*>(src + 0);
      int4 w1 = *reinterpret_cast<const int4*>(src + 8);
      *reinterpret_cast<int4*>(&B_lds[arow][t2 * 16 + 0]) = w0;
      *reinterpret_cast<int4*>(&B_lds[arow][t2 * 16 + 8]) = w1;
    }
    __syncthreads();
    short8v a[4], b[4];
    #pragma unroll
    for (int m = 0; m < 4; ++m)
      a[m] = *reinterpret_cast<const short8v*>(&A_lds[wr * 64 + m * 16 + l15][l4 * 8]);
    #pragma unroll
    for (int n = 0; n < 4; ++n)
      b[n] = *reinterpret_cast<const short8v*>(&B_lds[wc * 64 + n * 16 + l15][l4 * 8]);
    #pragma unroll
    for (int m = 0; m < 4; ++m)
      #pragma unroll
      for (int n = 0; n < 4; ++n)
        acc[m][n] = __builtin_amdgcn_mfma_f32_16x16x32_bf16(a[m], b[n], acc[m][n], 0, 0, 0);
    __syncthreads();
  }

  // epilogue: out = (1-b)*Xi + b*acc  (C/D: col = lane&15, row = (lane>>4)*4 + j)
  float b = beta_p[0], ob = 1.0f - b;
  int rb0 = row0 + wr * 64;
  int cb0 = wc * 64;
  #pragma unroll
  for (int m = 0; m < 4; ++m) {
    #pragma unroll
    for (int j = 0; j < 4; ++j) {
      int r = rb0 + m * 16 + l4 * 4 + j;
      if (r < nrows) {
        #pragma unroll
        for (int n = 0; n < 4; ++n) {
          size_t idx = (size_t)r * 256 + cb0 + n * 16 + l15;
          float xi = XiOut[idx];
          XiOut[idx] = ob * xi + b * acc[m][n][j];
        }
      }
    }
  }
}

// ---------------- launch ----------------

extern "C" void kernel_launch(void* const* d_in, const int* in_sizes, int n_in,
                              void* d_out, int out_size, void* d_ws, size_t ws_size,
                              hipStream_t stream) {
  const float* X     = (const float*)d_in[0];
  const float* X0    = (const float*)d_in[1];
  const float* W     = (const float*)d_in[2];
  const float* degV  = (const float*)d_in[3];
  const float* degE  = (const float*)d_in[4];
  const int*   vertex= (const int*)d_in[5];
  const int*   edges = (const int*)d_in[6];
  const float* alpha = (const float*)d_in[7];
  const float* beta  = (const float*)d_in[8];

  const int N   = in_sizes[3];   // degV has N elements
  const int M   = in_sizes[4];   // degE has M elements
  const int NNZ = in_sizes[5];

  auto r4 = [](int x) { return (x + 3) & ~3; };
  const int Mr = r4(M), Nr = r4(N);

  int* w = (int*)d_ws;
  int* cntE  = w; w += Mr;
  int* cntV  = w; w += Nr;        // contiguous with cntE for one memset
  int* offsE = w; w += r4(M + 1);
  int* offsV = w; w += r4(N + 1);
  int* curE  = w; w += Mr;
  int* curV  = w; w += Nr;
  int* bsum  = w; w += 128;
  int* bpre  = w; w += 128;
  ushort_t* incEv16 = (ushort_t*)w; w += (NNZ + 1) / 2;
  ushort_t* incVe16 = (ushort_t*)w; w += (NNZ + 1) / 2;
  uintptr_t p = (uintptr_t)w;
  p = (p + 15) & ~(uintptr_t)15;
  ushort_t* Wt = (ushort_t*)p;           // 256*256 bf16 = 128 KB
  p += (size_t)256 * 256 * sizeof(ushort_t);
  ushort_t* Xe = (ushort_t*)p;           // (M+1)*256 bf16 = 10.24 MB (+1 zero row)
  // total ws: ~0.85 MB ints + 1.6 MB inc16 + 0.13 MB Wt + 10.24 MB Xe ~= 12.8 MB
  // << proven-safe 24.5 MB footprint.

  float*    Xi  = (float*)d_out;         // N*256 f32 (hop2 output, GEMM in-place)
  ushort_t* Xbf = (ushort_t*)d_out;      // (N+1)*256 bf16 scratch inside d_out:
                                         // rows 0..N-1 = bf16(X), row N = zeros;
                                         // dead after hop1, overwritten by hop2/GEMM

  hipMemsetAsync(cntE, 0, (size_t)(Mr + Nr) * sizeof(int), stream);

  int nb = (NNZ + 255) / 256;
  k_wcvt <<<256, 256, 0, stream>>>(W, Wt, Xe + (size_t)M * DD, Xbf + (size_t)N * DD);
  k_xcvt <<<(N * (DD / 4) + 255) / 256, 256, 0, stream>>>(X, Xbf, N * (DD / 4));
  k_count<<<nb, 256, 0, stream>>>(vertex, edges, cntV, cntE, NNZ);
  k_bsum <<<2 * SNB, 256, 0, stream>>>(cntE, cntV, bsum, M, N);
  k_bscan<<<1, 128, 0, stream>>>(bsum, bpre, offsE, offsV, M, N);
  k_woffs<<<2 * SNB, 256, 0, stream>>>(cntE, cntV, bpre, offsE, curE, offsV, curV, M, N);
  k_fill <<<nb, 256, 0, stream>>>(vertex, edges, curE, curV, incEv16, incVe16, NNZ);

  k_hop1<<<(M + 3) / 4, 256, 0, stream>>>(Xbf, degE, offsE, incEv16, Xe, M, N);
  k_hop2<<<(N + 3) / 4, 256, 0, stream>>>(Xe, X0, degV, offsV, incVe16, alpha, Xi, N, M);
  k_gemm_mfma<<<(N + 127) / 128, 512, 0, stream>>>(Xi, Wt, beta, N);
}